// Round 1
// baseline (2038.293 us; speedup 1.0000x reference)
//
#include <hip/hip_runtime.h>
#include <hip/hip_bf16.h>
#include <math.h>

#define H_ 200
#define W_ 272
#define C_ 256
#define HW 54400
#define NANCH 489600
#define PRE_N 6000
#define POST_N 1000
#define NWORDS 94   // ceil(6000/64)

// ---- workspace layout (bytes) ----
#define X_OFF       0ull                 // 256*54400*4 = 55,705,600
#define CONF_OFF    55705600ull          // 489600*4   =  1,958,400
#define HIST1_OFF   57664000ull          // 65536*4    =    262,144
#define HIST2_OFF   57926144ull          // 65536*4    =    262,144
#define SCAL_OFF    58188288ull          // 64*4
#define SEL_OFF     58188544ull          // 8192*8     =     65,536
#define TOPIDX_OFF  58254080ull          // 6000*4
#define BOXES_OFF   58278080ull          // 6000*4*4
#define VALID_OFF   58374080ull          // 6000*4
#define MASK_OFF    58398080ull          // 6000*94*8  =  4,512,000
#define W1R_OFF     62910080ull          // 256*256*9*4 = 2,359,296
#define WCR_OFF     65269376ull          // 9*256*4
// total ~65,278,592 bytes

__device__ __forceinline__ unsigned fkey(float fv) {
    unsigned u = __float_as_uint(fv);
    return (u & 0x80000000u) ? ~u : (u | 0x80000000u);  // monotone: bigger float -> bigger key
}

// ---- clear histograms + scalars (contiguous 131,136 ints) ----
__global__ __launch_bounds__(256) void k_clear(unsigned* hist1) {
    int i = blockIdx.x * 256 + threadIdx.x;
    if (i < 131136) hist1[i] = 0u;
}

// ---- repack w1 (OIHW -> [ic][k][oc]) and w_cls ([a][c] -> [c][a]) ----
__global__ __launch_bounds__(256) void k_repack(const float* __restrict__ w1,
                                                const float* __restrict__ wcls,
                                                float* __restrict__ w1r,
                                                float* __restrict__ wcr) {
    int e = blockIdx.x * 256 + threadIdx.x;
    if (e < 589824) {
        int oc = e / 2304; int rem = e % 2304; int ic = rem / 9; int k = rem % 9;
        w1r[(ic * 9 + k) * 256 + oc] = w1[e];
    } else if (e < 589824 + 2304) {
        int e2 = e - 589824; int a = e2 / 256; int c = e2 % 256;
        wcr[c * 9 + a] = wcls[e2];
    }
}

// ---- 3x3 conv + bias + relu.  8x32 spatial tile, 32 oc per block ----
#define OCT 32
__global__ __launch_bounds__(256) void k_conv1(const float* __restrict__ f,
                                               const float* __restrict__ w1r,
                                               const float* __restrict__ b1,
                                               float* __restrict__ xo) {
    __shared__ float sIn[8 * 10 * 34];
    int tx = threadIdx.x & 31, ty = threadIdx.x >> 5;
    int x0 = blockIdx.x * 32, y0 = blockIdx.y * 8;
    int oc0 = blockIdx.z * OCT;
    int x = x0 + tx, y = y0 + ty;
    float acc[OCT];
#pragma unroll
    for (int o = 0; o < OCT; o++) acc[o] = 0.f;
    for (int ic0 = 0; ic0 < 256; ic0 += 8) {
        __syncthreads();
        for (int l = threadIdx.x; l < 2720; l += 256) {
            int ci = l / 340, rem = l % 340, yy = rem / 34, xx = rem % 34;
            int gx = x0 + xx - 1, gy = y0 + yy - 1;
            float v = 0.f;
            if (gx >= 0 && gx < W_ && gy >= 0 && gy < H_)
                v = f[(ic0 + ci) * HW + gy * W_ + gx];
            sIn[l] = v;
        }
        __syncthreads();
        for (int ci = 0; ci < 8; ci++) {
            const float* wbase = w1r + ((ic0 + ci) * 9) * 256 + oc0;  // uniform -> s_load
#pragma unroll
            for (int k = 0; k < 9; k++) {
                float iv = sIn[ci * 340 + (ty + k / 3) * 34 + tx + (k % 3)];
                const float* wp = wbase + k * 256;
#pragma unroll
                for (int o = 0; o < OCT; o++) acc[o] = fmaf(wp[o], iv, acc[o]);
            }
        }
    }
    if (x < W_ && y < H_) {
#pragma unroll
        for (int o = 0; o < OCT; o++) {
            float v = acc[o] + b1[oc0 + o];
            xo[(oc0 + o) * HW + y * W_ + x] = v > 0.f ? v : 0.f;
        }
    }
}

// ---- 1x1 cls conv -> conf[p*9+a] ----
__global__ __launch_bounds__(256) void k_cls(const float* __restrict__ x,
                                             const float* __restrict__ wcr,
                                             const float* __restrict__ bc,
                                             float* __restrict__ conf) {
    int p = blockIdx.x * 256 + threadIdx.x;
    if (p >= HW) return;
    float acc[9];
#pragma unroll
    for (int a = 0; a < 9; a++) acc[a] = 0.f;
    for (int c = 0; c < 256; c++) {
        float xv = x[c * HW + p];
        const float* wp = wcr + c * 9;  // uniform -> s_load
#pragma unroll
        for (int a = 0; a < 9; a++) acc[a] = fmaf(wp[a], xv, acc[a]);
    }
#pragma unroll
    for (int a = 0; a < 9; a++) conf[p * 9 + a] = acc[a] + bc[a];
}

// ---- radix-select histograms ----
__global__ __launch_bounds__(256) void k_hist1(const float* __restrict__ conf, unsigned* hist) {
    int n = blockIdx.x * 256 + threadIdx.x;
    if (n < NANCH) atomicAdd(&hist[fkey(conf[n]) >> 16], 1u);
}
__global__ __launch_bounds__(256) void k_hist2(const float* __restrict__ conf,
                                               const unsigned* __restrict__ scal, unsigned* hist) {
    int n = blockIdx.x * 256 + threadIdx.x;
    if (n >= NANCH) return;
    unsigned key = fkey(conf[n]);
    if ((key >> 16) == scal[0]) atomicAdd(&hist[key & 0xFFFFu], 1u);
}

// ---- descending scan of 65536-bin histogram, find bin of the target-th largest ----
__global__ __launch_bounds__(1024) void k_scan(const unsigned* __restrict__ hist,
                                               unsigned* scal, int mode) {
    __shared__ unsigned ssum[1024];
    int t = threadIdx.x;
    unsigned target = 6000u - (mode ? scal[1] : 0u);
    int base = 65535 - t * 64;
    unsigned s = 0;
    for (int k = 0; k < 64; k++) s += hist[base - k];
    ssum[t] = s;
    __syncthreads();
    for (int off = 1; off < 1024; off <<= 1) {
        unsigned v = (t >= off) ? ssum[t - off] : 0u;
        __syncthreads();
        ssum[t] += v;
        __syncthreads();
    }
    unsigned incl = ssum[t], excl = incl - s;
    if (excl < target && target <= incl) {
        unsigned run = excl;
        for (int k = 0; k < 64; k++) {
            unsigned c = hist[base - k];
            if (run + c >= target) { scal[2 * mode] = (unsigned)(base - k); scal[2 * mode + 1] = run; break; }
            run += c;
        }
    }
}

// ---- gather all keys >= threshold (ties after strict-greater block) ----
__global__ __launch_bounds__(256) void k_gather(const float* __restrict__ conf,
                                                unsigned* scal, unsigned long long* sel) {
    int n = blockIdx.x * 256 + threadIdx.x;
    if (n >= NANCH) return;
    unsigned B1 = scal[0], cnt1 = scal[1], B2 = scal[2], cnt2 = scal[3];
    unsigned T = (B1 << 16) | B2;
    unsigned key = fkey(conf[n]);
    if (key < T) return;
    unsigned long long kk = ((unsigned long long)(~key) << 32) | (unsigned)n;  // asc sort => score desc, idx asc
    if (key > T) {
        unsigned pos = atomicAdd(&scal[4], 1u);
        if (pos < 8192u) sel[pos] = kk;
    } else {
        unsigned pos = cnt1 + cnt2 + atomicAdd(&scal[5], 1u);
        if (pos < 8192u) sel[pos] = kk;
    }
}

// ---- one-block bitonic sort of 8192 keys, emit top-6000 indices ----
__global__ __launch_bounds__(1024) void k_sort(const unsigned* __restrict__ scal,
                                               const unsigned long long* __restrict__ sel,
                                               unsigned* __restrict__ topidx) {
    __shared__ unsigned long long sk[8192];
    unsigned G = scal[1] + scal[3];
    unsigned filled = G + scal[5];
    if (filled > 8192u) filled = 8192u;
    for (int i = threadIdx.x; i < 8192; i += 1024)
        sk[i] = (i < (int)filled) ? sel[i] : 0xFFFFFFFFFFFFFFFFull;
    __syncthreads();
    for (int k = 2; k <= 8192; k <<= 1) {
        for (int j = k >> 1; j > 0; j >>= 1) {
            for (int i = threadIdx.x; i < 8192; i += 1024) {
                int l = i ^ j;
                if (l > i) {
                    unsigned long long a = sk[i], b = sk[l];
                    bool up = ((i & k) == 0);
                    if ((a > b) == up) { sk[i] = b; sk[l] = a; }
                }
            }
            __syncthreads();
        }
    }
    for (int r = threadIdx.x; r < PRE_N; r += 1024)
        topidx[r] = (unsigned)(sk[r] & 0xFFFFFFFFull);
}

// ---- per-proposal: reg conv (4 channels), anchor, decode, clip, valid ----
__global__ __launch_bounds__(64) void k_prop(const float* __restrict__ x,
                                             const float* __restrict__ wreg,
                                             const float* __restrict__ breg,
                                             const unsigned* __restrict__ topidx,
                                             const int* __restrict__ imh, const int* __restrict__ imw,
                                             float* __restrict__ boxes, int* __restrict__ valid) {
    int r = blockIdx.x;
    int lane = threadIdx.x;
    unsigned n = topidx[r];
    int a = (int)(n % 9u); int p = (int)(n / 9u);
    const float* wr = wreg + (4 * a) * 256;
    float s0 = 0, s1 = 0, s2 = 0, s3 = 0;
    for (int c = lane; c < 256; c += 64) {
        float xv = x[c * HW + p];
        s0 = fmaf(wr[c], xv, s0);
        s1 = fmaf(wr[256 + c], xv, s1);
        s2 = fmaf(wr[512 + c], xv, s2);
        s3 = fmaf(wr[768 + c], xv, s3);
    }
#pragma unroll
    for (int off = 32; off >= 1; off >>= 1) {
        s0 += __shfl_down(s0, off);
        s1 += __shfl_down(s1, off);
        s2 += __shfl_down(s2, off);
        s3 += __shfl_down(s3, off);
    }
    if (lane == 0) {
        float dx = s0 + breg[4 * a], dy = s1 + breg[4 * a + 1];
        float dw = s2 + breg[4 * a + 2], dh = s3 + breg[4 * a + 3];
        int wi = p % W_, hi = p / W_;
        const double SC[3] = {32.0, 64.0, 128.0};
        const double RT[3] = {0.5, 1.0, 2.0};
        double sd = SC[a / 3], rd = RT[a % 3];
        double wb = sd * sqrt(1.0 / rd), hb = sd * sqrt(rd);
        // match numpy: base computed in f64, cast f32, then f32 add with shift
        float bx1 = (float)(-wb * 0.5), by1 = (float)(-hb * 0.5);
        float bx2 = (float)(wb * 0.5),  by2 = (float)(hb * 0.5);
        float cxs = ((float)wi + 0.5f) * 4.0f, cys = ((float)hi + 0.5f) * 4.0f;
        float x1a = cxs + bx1, y1a = cys + by1, x2a = cxs + bx2, y2a = cys + by2;
        float wa = x2a - x1a, ha = y2a - y1a;
        float cxa = x1a + 0.5f * wa, cya = y1a + 0.5f * ha;
        float cx = dx * wa + cxa, cy = dy * ha + cya;
        float ww = expf(dw) * wa, hh = expf(dh) * ha;
        float X1 = cx - 0.5f * ww, Y1 = cy - 0.5f * hh;
        float X2 = cx + 0.5f * ww, Y2 = cy + 0.5f * hh;
        float Wf = (float)(*imw), Hf = (float)(*imh);
        X1 = fminf(fmaxf(X1, 0.f), Wf); Y1 = fminf(fmaxf(Y1, 0.f), Hf);
        X2 = fminf(fmaxf(X2, 0.f), Wf); Y2 = fminf(fmaxf(Y2, 0.f), Hf);
        boxes[4 * r] = X1; boxes[4 * r + 1] = Y1; boxes[4 * r + 2] = X2; boxes[4 * r + 3] = Y2;
        valid[r] = ((X2 - X1) >= 1.0f && (Y2 - Y1) >= 1.0f) ? 1 : 0;
    }
}

// ---- NMS IoU bitmask: mask[i][jw] bit b = (j=jw*64+b > i) && iou>0.7 ----
__global__ __launch_bounds__(256) void k_mask(const float* __restrict__ boxes,
                                              unsigned long long* __restrict__ mask) {
    __shared__ float jb[256];
    int jw = blockIdx.x;
    int i = blockIdx.y * 256 + threadIdx.x;
    {
        int idx = jw * 256 + threadIdx.x;
        jb[threadIdx.x] = (idx < PRE_N * 4) ? boxes[idx] : 0.f;
    }
    __syncthreads();
    if (i >= PRE_N) return;
    float ax1 = boxes[4 * i], ay1 = boxes[4 * i + 1], ax2 = boxes[4 * i + 2], ay2 = boxes[4 * i + 3];
    float aarea = (ax2 - ax1) * (ay2 - ay1);
    unsigned long long m = 0;
    int jbase = jw * 64;
    for (int b = 0; b < 64; b++) {
        int j = jbase + b;
        if (j <= i || j >= PRE_N) continue;
        float bx1 = jb[4 * b], by1 = jb[4 * b + 1], bx2 = jb[4 * b + 2], by2 = jb[4 * b + 3];
        float barea = (bx2 - bx1) * (by2 - by1);
        float xx1 = fmaxf(ax1, bx1), yy1 = fmaxf(ay1, by1);
        float xx2 = fminf(ax2, bx2), yy2 = fminf(ay2, by2);
        float w = fmaxf(xx2 - xx1, 0.f), h = fmaxf(yy2 - yy1, 0.f);
        float inter = w * h;
        float iou = inter / (aarea + barea - inter + 1e-9f);
        if (iou > 0.7f) m |= (1ull << b);
    }
    mask[(size_t)i * NWORDS + jw] = m;
}

// ---- sequential greedy scan + compaction to d_out ----
__global__ __launch_bounds__(128) void k_scan_nms(const unsigned long long* __restrict__ mask,
                                                  const int* __restrict__ valid,
                                                  const float* __restrict__ boxes,
                                                  float* __restrict__ out) {
    __shared__ unsigned long long removed[NWORDS];
    __shared__ unsigned long long curm[64];
    __shared__ int vflag[64];
    __shared__ int keepList[POST_N];
    __shared__ int cnt;
    __shared__ unsigned long long keptbits;
    int t = threadIdx.x;
    if (t < NWORDS) removed[t] = 0ull;
    if (t == 0) cnt = 0;
    __syncthreads();
    for (int w = 0; w < NWORDS; w++) {
        if (t < 64) {
            int i = w * 64 + t;
            curm[t] = (i < PRE_N) ? mask[(size_t)i * NWORDS + w] : 0ull;
            vflag[t] = (i < PRE_N) ? valid[i] : 0;
        }
        __syncthreads();
        if (t == 0) {
            unsigned long long rm = removed[w];
            unsigned long long kb = 0ull;
            int c = cnt;
            for (int b = 0; b < 64; b++) {
                int i = w * 64 + b;
                if (i >= PRE_N || c >= POST_N) break;
                if (!((rm >> b) & 1ull) && vflag[b]) {
                    keepList[c++] = i;
                    kb |= (1ull << b);
                    rm |= curm[b];
                }
            }
            cnt = c;
            keptbits = kb;
        }
        __syncthreads();
        if (cnt >= POST_N) break;
        unsigned long long kb = keptbits;
        if (kb) {
            for (int w2 = w + 1 + t; w2 < NWORDS; w2 += 128) {
                unsigned long long acc = removed[w2];
                unsigned long long tt = kb;
                while (tt) {
                    int b = __ffsll((unsigned long long)tt) - 1;
                    tt &= tt - 1;
                    acc |= mask[(size_t)(w * 64 + b) * NWORDS + w2];
                }
                removed[w2] = acc;
            }
        }
        __syncthreads();
    }
    __syncthreads();
    int c = cnt;
    for (int e = t; e < POST_N * 4; e += 128) {
        int r = e >> 2;
        out[e] = (r < c) ? boxes[4 * keepList[r] + (e & 3)] : 0.f;
    }
}

extern "C" void kernel_launch(void* const* d_in, const int* in_sizes, int n_in,
                              void* d_out, int out_size, void* d_ws, size_t ws_size,
                              hipStream_t stream) {
    const float* feature = (const float*)d_in[0];
    const float* w1   = (const float*)d_in[1];
    const float* b1   = (const float*)d_in[2];
    const float* wcls = (const float*)d_in[3];
    const float* bcls = (const float*)d_in[4];
    const float* wreg = (const float*)d_in[5];
    const float* breg = (const float*)d_in[6];
    const int* imh = (const int*)d_in[7];
    const int* imw = (const int*)d_in[8];

    char* ws = (char*)d_ws;
    float* xbuf  = (float*)(ws + X_OFF);
    float* conf  = (float*)(ws + CONF_OFF);
    unsigned* hist1 = (unsigned*)(ws + HIST1_OFF);
    unsigned* hist2 = (unsigned*)(ws + HIST2_OFF);
    unsigned* scal  = (unsigned*)(ws + SCAL_OFF);
    unsigned long long* sel = (unsigned long long*)(ws + SEL_OFF);
    unsigned* topidx = (unsigned*)(ws + TOPIDX_OFF);
    float* boxes = (float*)(ws + BOXES_OFF);
    int* valid   = (int*)(ws + VALID_OFF);
    unsigned long long* mask = (unsigned long long*)(ws + MASK_OFF);
    float* w1r = (float*)(ws + W1R_OFF);
    float* wcr = (float*)(ws + WCR_OFF);
    float* outF = (float*)d_out;

    hipLaunchKernelGGL(k_clear,  dim3(513),  dim3(256), 0, stream, hist1);
    hipLaunchKernelGGL(k_repack, dim3(2313), dim3(256), 0, stream, w1, wcls, w1r, wcr);
    hipLaunchKernelGGL(k_conv1,  dim3(9, 25, 8), dim3(256), 0, stream, feature, w1r, b1, xbuf);
    hipLaunchKernelGGL(k_cls,    dim3(213),  dim3(256), 0, stream, xbuf, wcr, bcls, conf);
    hipLaunchKernelGGL(k_hist1,  dim3(1913), dim3(256), 0, stream, conf, hist1);
    hipLaunchKernelGGL(k_scan,   dim3(1),    dim3(1024), 0, stream, hist1, scal, 0);
    hipLaunchKernelGGL(k_hist2,  dim3(1913), dim3(256), 0, stream, conf, scal, hist2);
    hipLaunchKernelGGL(k_scan,   dim3(1),    dim3(1024), 0, stream, hist2, scal, 1);
    hipLaunchKernelGGL(k_gather, dim3(1913), dim3(256), 0, stream, conf, scal, sel);
    hipLaunchKernelGGL(k_sort,   dim3(1),    dim3(1024), 0, stream, scal, sel, topidx);
    hipLaunchKernelGGL(k_prop,   dim3(PRE_N), dim3(64), 0, stream, xbuf, wreg, breg, topidx, imh, imw, boxes, valid);
    hipLaunchKernelGGL(k_mask,   dim3(NWORDS, 24), dim3(256), 0, stream, boxes, mask);
    hipLaunchKernelGGL(k_scan_nms, dim3(1), dim3(128), 0, stream, mask, valid, boxes, outF);
}

// Round 2
// 1996.551 us; speedup vs baseline: 1.0209x; 1.0209x over previous
//
#include <hip/hip_runtime.h>
#include <hip/hip_bf16.h>
#include <math.h>

#define H_ 200
#define W_ 272
#define C_ 256
#define HW 54400
#define NANCH 489600
#define PRE_N 6000
#define POST_N 1000
#define NWORDS 94   // ceil(6000/64)

// ---- workspace layout (bytes) ----
#define X_OFF       0ull                 // 256*54400*4 = 55,705,600
#define CONF_OFF    55705600ull          // 489600*4   =  1,958,400
#define HIST1_OFF   57664000ull          // 65536*4    =    262,144
#define HIST2_OFF   57926144ull          // 65536*4    =    262,144
#define SCAL_OFF    58188288ull          // 64*4
#define SEL_OFF     58188544ull          // 8192*8     =     65,536
#define TOPIDX_OFF  58254080ull          // 6000*4
#define BOXES_OFF   58278080ull          // 6000*4*4
#define VALID_OFF   58374080ull          // 6000*4
#define MASK_OFF    58398080ull          // 6000*94*8  =  4,512,000
#define W1R_OFF     62910080ull          // [2][256][9][128]*4 = 2,359,296
#define WCR_OFF     65269376ull          // 9*256*4

__device__ __forceinline__ unsigned fkey(float fv) {
    unsigned u = __float_as_uint(fv);
    return (u & 0x80000000u) ? ~u : (u | 0x80000000u);  // monotone: bigger float -> bigger key
}

// ---- clear histograms + repack weights, one launch ----
__global__ __launch_bounds__(256) void k_init(const float* __restrict__ w1,
                                              const float* __restrict__ wcls,
                                              unsigned* __restrict__ hist1,
                                              float* __restrict__ w1r,
                                              float* __restrict__ wcr) {
    int e = blockIdx.x * 256 + threadIdx.x;
    if (e < 131136) hist1[e] = 0u;
    int e1 = e - 131136;
    if (e1 >= 0 && e1 < 589824) {
        int oc = e1 / 2304; int rem = e1 % 2304; int ic = rem / 9; int k = rem % 9;
        int half = oc >> 7, ocl = oc & 127;
        // layout [half][ic][k][ocl] -> per-block chunk is fully contiguous
        w1r[(((half * 256 + ic) * 9) + k) * 128 + ocl] = w1[e1];
    } else if (e1 >= 589824 && e1 < 589824 + 2304) {
        int e2 = e1 - 589824; int a = e2 / 256; int c = e2 % 256;
        wcr[c * 9 + a] = wcls[e2];
    }
}

// ---- 3x3 conv + bias + relu. Register-tiled implicit GEMM. ----
// Block: 32x * 4y * 128oc, 256 threads. Thread: 8x * 8oc (64 acc VGPRs).
// Weights staged to LDS per 8-ic chunk (contiguous), read via ds_read_b128.
// Accumulation order (ic -> ky -> kx) matches the previous kernel bitwise.
__global__ __launch_bounds__(256) void k_conv1(const float* __restrict__ f,
                                               const float* __restrict__ w1r,
                                               const float* __restrict__ b1,
                                               float* __restrict__ xo) {
    __shared__ float sW[8 * 9 * 128];   // 36 KB
    __shared__ float sI[8 * 6 * 36];    // 6.75 KB (34 used per row, 36 stride for alignment)
    int tid = threadIdx.x;
    int ocg = tid & 15;          // 16 oc groups of 8 (fastest -> LDS weight reads conflict-free)
    int sp  = tid >> 4;          // 16 spatial groups
    int xg  = sp & 3;            // 4 x-subtiles of 8
    int yg  = sp >> 2;           // 4 rows
    int X0 = blockIdx.x * 32;
    int Y0 = blockIdx.y * 4;
    int z  = blockIdx.z;         // oc half
    int ocl = ocg * 8;
    int y = Y0 + yg;
    int xbase = X0 + xg * 8;

    float acc[8][8];
#pragma unroll
    for (int j = 0; j < 8; j++)
#pragma unroll
        for (int i = 0; i < 8; i++) acc[j][i] = 0.f;

    for (int ic0 = 0; ic0 < 256; ic0 += 8) {
        __syncthreads();
        // stage weights: 9216 contiguous floats = 2304 float4
        {
            const float4* wsrc = (const float4*)(w1r + ((size_t)(z * 256 + ic0) * 9) * 128);
            float4* wdst = (float4*)sW;
            for (int i = tid; i < 2304; i += 256) wdst[i] = wsrc[i];
        }
        // stage input halo tile: 8 ic x 6 rows x 34
        for (int l = tid; l < 1632; l += 256) {
            int ci = l / 204; int r = l - ci * 204; int ry = r / 34; int rx = r - ry * 34;
            int gx = X0 - 1 + rx, gy = Y0 - 1 + ry;
            float v = 0.f;
            if (gx >= 0 && gx < W_ && gy >= 0 && gy < H_)
                v = f[(ic0 + ci) * HW + gy * W_ + gx];
            sI[(ci * 6 + ry) * 36 + rx] = v;
        }
        __syncthreads();
        for (int ci = 0; ci < 8; ci++) {
#pragma unroll
            for (int ky = 0; ky < 3; ky++) {
                const float4* ip = (const float4*)&sI[(ci * 6 + yg + ky) * 36 + xg * 8];
                float4 a0 = ip[0], a1 = ip[1], a2 = ip[2];
                float in[12] = {a0.x, a0.y, a0.z, a0.w, a1.x, a1.y, a1.z, a1.w,
                                a2.x, a2.y, a2.z, a2.w};
#pragma unroll
                for (int kx = 0; kx < 3; kx++) {
                    const float4* wp = (const float4*)&sW[(ci * 9 + ky * 3 + kx) * 128 + ocl];
                    float4 w0 = wp[0], w1v = wp[1];
                    float wreg[8] = {w0.x, w0.y, w0.z, w0.w, w1v.x, w1v.y, w1v.z, w1v.w};
#pragma unroll
                    for (int j = 0; j < 8; j++)
#pragma unroll
                        for (int i = 0; i < 8; i++)
                            acc[j][i] = fmaf(wreg[j], in[i + kx], acc[j][i]);
                }
            }
        }
    }
    // epilogue: bias + relu + store (y always < 200; x may exceed 271 on last x-block)
#pragma unroll
    for (int j = 0; j < 8; j++) {
        int oc = z * 128 + ocl + j;
        float bv = b1[oc];
        float* orow = xo + (size_t)oc * HW + y * W_ + xbase;
        float v0 = fmaxf(acc[j][0] + bv, 0.f), v1 = fmaxf(acc[j][1] + bv, 0.f);
        float v2 = fmaxf(acc[j][2] + bv, 0.f), v3 = fmaxf(acc[j][3] + bv, 0.f);
        float v4 = fmaxf(acc[j][4] + bv, 0.f), v5 = fmaxf(acc[j][5] + bv, 0.f);
        float v6 = fmaxf(acc[j][6] + bv, 0.f), v7 = fmaxf(acc[j][7] + bv, 0.f);
        if (xbase + 7 < W_) {
            ((float4*)orow)[0] = make_float4(v0, v1, v2, v3);
            ((float4*)orow)[1] = make_float4(v4, v5, v6, v7);
        } else {
            float vv[8] = {v0, v1, v2, v3, v4, v5, v6, v7};
            for (int i = 0; i < 8; i++)
                if (xbase + i < W_) orow[i] = vv[i];
        }
    }
}

// ---- 1x1 cls conv -> conf[p*9+a] ----
__global__ __launch_bounds__(256) void k_cls(const float* __restrict__ x,
                                             const float* __restrict__ wcr,
                                             const float* __restrict__ bc,
                                             float* __restrict__ conf) {
    int p = blockIdx.x * 256 + threadIdx.x;
    if (p >= HW) return;
    float acc[9];
#pragma unroll
    for (int a = 0; a < 9; a++) acc[a] = 0.f;
    for (int c = 0; c < 256; c++) {
        float xv = x[c * HW + p];
        const float* wp = wcr + c * 9;  // uniform -> s_load
#pragma unroll
        for (int a = 0; a < 9; a++) acc[a] = fmaf(wp[a], xv, acc[a]);
    }
#pragma unroll
    for (int a = 0; a < 9; a++) conf[p * 9 + a] = acc[a] + bc[a];
}

// ---- radix-select histograms ----
__global__ __launch_bounds__(256) void k_hist1(const float* __restrict__ conf, unsigned* hist) {
    int n = blockIdx.x * 256 + threadIdx.x;
    if (n < NANCH) atomicAdd(&hist[fkey(conf[n]) >> 16], 1u);
}
__global__ __launch_bounds__(256) void k_hist2(const float* __restrict__ conf,
                                               const unsigned* __restrict__ scal, unsigned* hist) {
    int n = blockIdx.x * 256 + threadIdx.x;
    if (n >= NANCH) return;
    unsigned key = fkey(conf[n]);
    if ((key >> 16) == scal[0]) atomicAdd(&hist[key & 0xFFFFu], 1u);
}

// ---- descending scan of 65536-bin histogram, find bin of the target-th largest ----
__global__ __launch_bounds__(1024) void k_scan(const unsigned* __restrict__ hist,
                                               unsigned* scal, int mode) {
    __shared__ unsigned ssum[1024];
    int t = threadIdx.x;
    unsigned target = 6000u - (mode ? scal[1] : 0u);
    int base = 65535 - t * 64;
    unsigned s = 0;
    for (int k = 0; k < 64; k++) s += hist[base - k];
    ssum[t] = s;
    __syncthreads();
    for (int off = 1; off < 1024; off <<= 1) {
        unsigned v = (t >= off) ? ssum[t - off] : 0u;
        __syncthreads();
        ssum[t] += v;
        __syncthreads();
    }
    unsigned incl = ssum[t], excl = incl - s;
    if (excl < target && target <= incl) {
        unsigned run = excl;
        for (int k = 0; k < 64; k++) {
            unsigned c = hist[base - k];
            if (run + c >= target) { scal[2 * mode] = (unsigned)(base - k); scal[2 * mode + 1] = run; break; }
            run += c;
        }
    }
}

// ---- gather all keys >= threshold (ties after strict-greater block) ----
__global__ __launch_bounds__(256) void k_gather(const float* __restrict__ conf,
                                                unsigned* scal, unsigned long long* sel) {
    int n = blockIdx.x * 256 + threadIdx.x;
    if (n >= NANCH) return;
    unsigned B1 = scal[0], cnt1 = scal[1], B2 = scal[2], cnt2 = scal[3];
    unsigned T = (B1 << 16) | B2;
    unsigned key = fkey(conf[n]);
    if (key < T) return;
    unsigned long long kk = ((unsigned long long)(~key) << 32) | (unsigned)n;  // asc sort => score desc, idx asc
    if (key > T) {
        unsigned pos = atomicAdd(&scal[4], 1u);
        if (pos < 8192u) sel[pos] = kk;
    } else {
        unsigned pos = cnt1 + cnt2 + atomicAdd(&scal[5], 1u);
        if (pos < 8192u) sel[pos] = kk;
    }
}

// ---- one-block bitonic sort of 8192 keys, emit top-6000 indices ----
__global__ __launch_bounds__(1024) void k_sort(const unsigned* __restrict__ scal,
                                               const unsigned long long* __restrict__ sel,
                                               unsigned* __restrict__ topidx) {
    __shared__ unsigned long long sk[8192];
    unsigned G = scal[1] + scal[3];
    unsigned filled = G + scal[5];
    if (filled > 8192u) filled = 8192u;
    for (int i = threadIdx.x; i < 8192; i += 1024)
        sk[i] = (i < (int)filled) ? sel[i] : 0xFFFFFFFFFFFFFFFFull;
    __syncthreads();
    for (int k = 2; k <= 8192; k <<= 1) {
        for (int j = k >> 1; j > 0; j >>= 1) {
            for (int i = threadIdx.x; i < 8192; i += 1024) {
                int l = i ^ j;
                if (l > i) {
                    unsigned long long a = sk[i], b = sk[l];
                    bool up = ((i & k) == 0);
                    if ((a > b) == up) { sk[i] = b; sk[l] = a; }
                }
            }
            __syncthreads();
        }
    }
    for (int r = threadIdx.x; r < PRE_N; r += 1024)
        topidx[r] = (unsigned)(sk[r] & 0xFFFFFFFFull);
}

// ---- per-proposal: reg conv (4 channels), anchor, decode, clip, valid ----
__global__ __launch_bounds__(64) void k_prop(const float* __restrict__ x,
                                             const float* __restrict__ wreg,
                                             const float* __restrict__ breg,
                                             const unsigned* __restrict__ topidx,
                                             const int* __restrict__ imh, const int* __restrict__ imw,
                                             float* __restrict__ boxes, int* __restrict__ valid) {
    int r = blockIdx.x;
    int lane = threadIdx.x;
    unsigned n = topidx[r];
    int a = (int)(n % 9u); int p = (int)(n / 9u);
    const float* wr = wreg + (4 * a) * 256;
    float s0 = 0, s1 = 0, s2 = 0, s3 = 0;
    for (int c = lane; c < 256; c += 64) {
        float xv = x[c * HW + p];
        s0 = fmaf(wr[c], xv, s0);
        s1 = fmaf(wr[256 + c], xv, s1);
        s2 = fmaf(wr[512 + c], xv, s2);
        s3 = fmaf(wr[768 + c], xv, s3);
    }
#pragma unroll
    for (int off = 32; off >= 1; off >>= 1) {
        s0 += __shfl_down(s0, off);
        s1 += __shfl_down(s1, off);
        s2 += __shfl_down(s2, off);
        s3 += __shfl_down(s3, off);
    }
    if (lane == 0) {
        float dx = s0 + breg[4 * a], dy = s1 + breg[4 * a + 1];
        float dw = s2 + breg[4 * a + 2], dh = s3 + breg[4 * a + 3];
        int wi = p % W_, hi = p / W_;
        const double SC[3] = {32.0, 64.0, 128.0};
        const double RT[3] = {0.5, 1.0, 2.0};
        double sd = SC[a / 3], rd = RT[a % 3];
        double wb = sd * sqrt(1.0 / rd), hb = sd * sqrt(rd);
        float bx1 = (float)(-wb * 0.5), by1 = (float)(-hb * 0.5);
        float bx2 = (float)(wb * 0.5),  by2 = (float)(hb * 0.5);
        float cxs = ((float)wi + 0.5f) * 4.0f, cys = ((float)hi + 0.5f) * 4.0f;
        float x1a = cxs + bx1, y1a = cys + by1, x2a = cxs + bx2, y2a = cys + by2;
        float wa = x2a - x1a, ha = y2a - y1a;
        float cxa = x1a + 0.5f * wa, cya = y1a + 0.5f * ha;
        float cx = dx * wa + cxa, cy = dy * ha + cya;
        float ww = expf(dw) * wa, hh = expf(dh) * ha;
        float X1 = cx - 0.5f * ww, Y1 = cy - 0.5f * hh;
        float X2 = cx + 0.5f * ww, Y2 = cy + 0.5f * hh;
        float Wf = (float)(*imw), Hf = (float)(*imh);
        X1 = fminf(fmaxf(X1, 0.f), Wf); Y1 = fminf(fmaxf(Y1, 0.f), Hf);
        X2 = fminf(fmaxf(X2, 0.f), Wf); Y2 = fminf(fmaxf(Y2, 0.f), Hf);
        boxes[4 * r] = X1; boxes[4 * r + 1] = Y1; boxes[4 * r + 2] = X2; boxes[4 * r + 3] = Y2;
        valid[r] = ((X2 - X1) >= 1.0f && (Y2 - Y1) >= 1.0f) ? 1 : 0;
    }
}

// ---- NMS IoU bitmask: mask[i][jw] bit b = (j=jw*64+b > i) && iou>0.7 ----
__global__ __launch_bounds__(256) void k_mask(const float* __restrict__ boxes,
                                              unsigned long long* __restrict__ mask) {
    __shared__ float jb[256];
    int jw = blockIdx.x;
    int i = blockIdx.y * 256 + threadIdx.x;
    {
        int idx = jw * 256 + threadIdx.x;
        jb[threadIdx.x] = (idx < PRE_N * 4) ? boxes[idx] : 0.f;
    }
    __syncthreads();
    if (i >= PRE_N) return;
    float ax1 = boxes[4 * i], ay1 = boxes[4 * i + 1], ax2 = boxes[4 * i + 2], ay2 = boxes[4 * i + 3];
    float aarea = (ax2 - ax1) * (ay2 - ay1);
    unsigned long long m = 0;
    int jbase = jw * 64;
    for (int b = 0; b < 64; b++) {
        int j = jbase + b;
        if (j <= i || j >= PRE_N) continue;
        float bx1 = jb[4 * b], by1 = jb[4 * b + 1], bx2 = jb[4 * b + 2], by2 = jb[4 * b + 3];
        float barea = (bx2 - bx1) * (by2 - by1);
        float xx1 = fmaxf(ax1, bx1), yy1 = fmaxf(ay1, by1);
        float xx2 = fminf(ax2, bx2), yy2 = fminf(ay2, by2);
        float w = fmaxf(xx2 - xx1, 0.f), h = fmaxf(yy2 - yy1, 0.f);
        float inter = w * h;
        float iou = inter / (aarea + barea - inter + 1e-9f);
        if (iou > 0.7f) m |= (1ull << b);
    }
    mask[(size_t)i * NWORDS + jw] = m;
}

// ---- greedy scan: serial part iterates only candidate bits ----
__global__ __launch_bounds__(128) void k_scan_nms(const unsigned long long* __restrict__ mask,
                                                  const int* __restrict__ valid,
                                                  const float* __restrict__ boxes,
                                                  float* __restrict__ out) {
    __shared__ unsigned long long removed[NWORDS];
    __shared__ unsigned long long validw[NWORDS];
    __shared__ unsigned long long curm[64];
    __shared__ int keepList[POST_N];
    __shared__ int cnt;
    __shared__ unsigned long long keptbits;
    int t = threadIdx.x;
    if (t < NWORDS) { removed[t] = 0ull; validw[t] = 0ull; }
    if (t == 0) cnt = 0;
    __syncthreads();
    for (int i = t; i < PRE_N; i += 128)
        if (valid[i]) atomicOr(&validw[i >> 6], 1ull << (i & 63));
    __syncthreads();
    for (int w = 0; w < NWORDS; w++) {
        unsigned long long candw = validw[w] & ~removed[w];  // uniform (LDS, post-sync)
        if (!candw) continue;
        if (t < 64) curm[t] = ((candw >> t) & 1ull) ? mask[(size_t)(w * 64 + t) * NWORDS + w] : 0ull;
        __syncthreads();
        if (t == 0) {
            unsigned long long cand = candw;
            unsigned long long kb = 0ull;
            int c = cnt;
            while (cand && c < POST_N) {
                int b = __ffsll((unsigned long long)cand) - 1;
                keepList[c++] = w * 64 + b;
                kb |= 1ull << b;
                cand &= ~(1ull << b);
                cand &= ~curm[b];
            }
            cnt = c; keptbits = kb;
        }
        __syncthreads();
        if (cnt >= POST_N) break;
        unsigned long long kb = keptbits;
        if (kb) {
            for (int w2 = w + 1 + t; w2 < NWORDS; w2 += 128) {
                unsigned long long acc2 = removed[w2];
                unsigned long long tt = kb;
                while (tt) {
                    int b = __ffsll((unsigned long long)tt) - 1;
                    tt &= tt - 1;
                    acc2 |= mask[(size_t)(w * 64 + b) * NWORDS + w2];
                }
                removed[w2] = acc2;
            }
        }
        __syncthreads();
    }
    __syncthreads();
    int c = cnt;
    for (int e = t; e < POST_N * 4; e += 128) {
        int r = e >> 2;
        out[e] = (r < c) ? boxes[4 * keepList[r] + (e & 3)] : 0.f;
    }
}

extern "C" void kernel_launch(void* const* d_in, const int* in_sizes, int n_in,
                              void* d_out, int out_size, void* d_ws, size_t ws_size,
                              hipStream_t stream) {
    const float* feature = (const float*)d_in[0];
    const float* w1   = (const float*)d_in[1];
    const float* b1   = (const float*)d_in[2];
    const float* wcls = (const float*)d_in[3];
    const float* bcls = (const float*)d_in[4];
    const float* wreg = (const float*)d_in[5];
    const float* breg = (const float*)d_in[6];
    const int* imh = (const int*)d_in[7];
    const int* imw = (const int*)d_in[8];

    char* ws = (char*)d_ws;
    float* xbuf  = (float*)(ws + X_OFF);
    float* conf  = (float*)(ws + CONF_OFF);
    unsigned* hist1 = (unsigned*)(ws + HIST1_OFF);
    unsigned* hist2 = (unsigned*)(ws + HIST2_OFF);
    unsigned* scal  = (unsigned*)(ws + SCAL_OFF);
    unsigned long long* sel = (unsigned long long*)(ws + SEL_OFF);
    unsigned* topidx = (unsigned*)(ws + TOPIDX_OFF);
    float* boxes = (float*)(ws + BOXES_OFF);
    int* valid   = (int*)(ws + VALID_OFF);
    unsigned long long* mask = (unsigned long long*)(ws + MASK_OFF);
    float* w1r = (float*)(ws + W1R_OFF);
    float* wcr = (float*)(ws + WCR_OFF);
    float* outF = (float*)d_out;

    hipLaunchKernelGGL(k_init,   dim3(2826), dim3(256), 0, stream, w1, wcls, hist1, w1r, wcr);
    hipLaunchKernelGGL(k_conv1,  dim3(9, 50, 2), dim3(256), 0, stream, feature, w1r, b1, xbuf);
    hipLaunchKernelGGL(k_cls,    dim3(213),  dim3(256), 0, stream, xbuf, wcr, bcls, conf);
    hipLaunchKernelGGL(k_hist1,  dim3(1913), dim3(256), 0, stream, conf, hist1);
    hipLaunchKernelGGL(k_scan,   dim3(1),    dim3(1024), 0, stream, hist1, scal, 0);
    hipLaunchKernelGGL(k_hist2,  dim3(1913), dim3(256), 0, stream, conf, scal, hist2);
    hipLaunchKernelGGL(k_scan,   dim3(1),    dim3(1024), 0, stream, hist2, scal, 1);
    hipLaunchKernelGGL(k_gather, dim3(1913), dim3(256), 0, stream, conf, scal, sel);
    hipLaunchKernelGGL(k_sort,   dim3(1),    dim3(1024), 0, stream, scal, sel, topidx);
    hipLaunchKernelGGL(k_prop,   dim3(PRE_N), dim3(64), 0, stream, xbuf, wreg, breg, topidx, imh, imw, boxes, valid);
    hipLaunchKernelGGL(k_mask,   dim3(NWORDS, 24), dim3(256), 0, stream, boxes, mask);
    hipLaunchKernelGGL(k_scan_nms, dim3(1), dim3(128), 0, stream, mask, valid, boxes, outF);
}

// Round 3
// 1829.037 us; speedup vs baseline: 1.1144x; 1.0916x over previous
//
#include <hip/hip_runtime.h>
#include <hip/hip_bf16.h>
#include <math.h>

#define H_ 200
#define W_ 272
#define C_ 256
#define HW 54400
#define NANCH 489600
#define PRE_N 6000
#define POST_N 1000
#define NWORDS 94   // ceil(6000/64)

// ---- workspace layout (bytes) ----
#define X_OFF       0ull                 // 256*54400*4 = 55,705,600
#define CONF_OFF    55705600ull          // 489600*4   =  1,958,400
#define HIST1_OFF   57664000ull          // 65536*4    =    262,144
#define HIST2_OFF   57926144ull          // 65536*4    =    262,144
#define SCAL_OFF    58188288ull          // 64*4
#define SEL_OFF     58188544ull          // 8192*8     =     65,536
#define TOPIDX_OFF  58254080ull          // 6000*4
#define BOXES_OFF   58278080ull          // 6000*4*4
#define VALID_OFF   58374080ull          // 6000*4
#define MASK_OFF    58398080ull          // 6000*94*8  =  4,512,000
#define W1R_OFF     62910080ull          // [4][256][9][64]*4 = 2,359,296
#define WCR_OFF     65269376ull          // 9*256*4

__device__ __forceinline__ unsigned fkey(float fv) {
    unsigned u = __float_as_uint(fv);
    return (u & 0x80000000u) ? ~u : (u | 0x80000000u);  // monotone: bigger float -> bigger key
}

// ---- clear histograms + repack weights, one launch ----
__global__ __launch_bounds__(256) void k_init(const float* __restrict__ w1,
                                              const float* __restrict__ wcls,
                                              unsigned* __restrict__ hist1,
                                              float* __restrict__ w1r,
                                              float* __restrict__ wcr) {
    int e = blockIdx.x * 256 + threadIdx.x;
    if (e < 131136) hist1[e] = 0u;
    int e1 = e - 131136;
    if (e1 >= 0 && e1 < 589824) {
        int oc = e1 / 2304; int rem = e1 % 2304; int ic = rem / 9; int k = rem % 9;
        int q = oc >> 6, ocl = oc & 63;
        // layout [quarter][ic][k][ocl] -> per-block chunk fully contiguous
        w1r[(((q * 256 + ic) * 9) + k) * 64 + ocl] = w1[e1];
    } else if (e1 >= 589824 && e1 < 589824 + 2304) {
        int e2 = e1 - 589824; int a = e2 / 256; int c = e2 % 256;
        wcr[c * 9 + a] = wcls[e2];
    }
}

// ---- 3x3 conv + bias + relu. Register-tiled implicit GEMM. ----
// Block: 32x * 8y * 64oc, 256 threads. Thread: 8x * 8oc (64 acc VGPRs).
// LDS 29.9 KB -> 5 blocks/CU (20 waves). Weight reads <=2-way bank alias (free),
// input reads conflict-free. Accumulation order ic->ky->kx (bitwise-stable).
__global__ __launch_bounds__(256) void k_conv1(const float* __restrict__ f,
                                               const float* __restrict__ w1r,
                                               const float* __restrict__ b1,
                                               float* __restrict__ xo) {
    __shared__ float sW[8 * 9 * 64];    // 18,432 B
    __shared__ float sI[8 * 10 * 36];   // 11,520 B (34 used/row, stride 36)
    int tid = threadIdx.x;
    int ocg = tid & 7;            // 8 oc-groups of 8
    int xg  = (tid >> 3) & 3;     // 4 x-subtiles of 8
    int yg  = tid >> 5;           // 8 rows
    int X0 = blockIdx.x * 32;
    int Y0 = blockIdx.y * 8;
    int q  = blockIdx.z;          // oc quarter
    int ocl = ocg * 8;
    int y = Y0 + yg;
    int xbase = X0 + xg * 8;

    float acc[8][8];
#pragma unroll
    for (int j = 0; j < 8; j++)
#pragma unroll
        for (int i = 0; i < 8; i++) acc[j][i] = 0.f;

    for (int ic0 = 0; ic0 < 256; ic0 += 8) {
        __syncthreads();
        // stage weights: 4608 contiguous floats = 1152 float4
        {
            const float4* wsrc = (const float4*)(w1r + ((size_t)(q * 256 + ic0) * 9) * 64);
            float4* wdst = (float4*)sW;
            for (int i = tid; i < 1152; i += 256) wdst[i] = wsrc[i];
        }
        // stage input halo tile: 8 ic x 10 rows x 34 cols
        for (int l = tid; l < 2720; l += 256) {
            int ci = l / 340; int r = l - ci * 340; int ry = r / 34; int rx = r - ry * 34;
            int gx = X0 - 1 + rx, gy = Y0 - 1 + ry;
            float v = 0.f;
            if (gx >= 0 && gx < W_ && gy >= 0 && gy < H_)
                v = f[(ic0 + ci) * HW + gy * W_ + gx];
            sI[(ci * 10 + ry) * 36 + rx] = v;
        }
        __syncthreads();
        for (int ci = 0; ci < 8; ci++) {
#pragma unroll
            for (int ky = 0; ky < 3; ky++) {
                const float4* ip = (const float4*)&sI[(ci * 10 + yg + ky) * 36 + xg * 8];
                float4 a0 = ip[0], a1 = ip[1], a2 = ip[2];
                float in[12] = {a0.x, a0.y, a0.z, a0.w, a1.x, a1.y, a1.z, a1.w,
                                a2.x, a2.y, a2.z, a2.w};
#pragma unroll
                for (int kx = 0; kx < 3; kx++) {
                    const float4* wp = (const float4*)&sW[(ci * 9 + ky * 3 + kx) * 64 + ocl];
                    float4 w0 = wp[0], w1v = wp[1];
                    float wreg[8] = {w0.x, w0.y, w0.z, w0.w, w1v.x, w1v.y, w1v.z, w1v.w};
#pragma unroll
                    for (int j = 0; j < 8; j++)
#pragma unroll
                        for (int i = 0; i < 8; i++)
                            acc[j][i] = fmaf(wreg[j], in[i + kx], acc[j][i]);
                }
            }
        }
    }
    // epilogue: bias + relu + store (y always < 200; x may exceed 271 on last x-block)
#pragma unroll
    for (int j = 0; j < 8; j++) {
        int oc = q * 64 + ocl + j;
        float bv = b1[oc];
        float* orow = xo + (size_t)oc * HW + y * W_ + xbase;
        float v0 = fmaxf(acc[j][0] + bv, 0.f), v1 = fmaxf(acc[j][1] + bv, 0.f);
        float v2 = fmaxf(acc[j][2] + bv, 0.f), v3 = fmaxf(acc[j][3] + bv, 0.f);
        float v4 = fmaxf(acc[j][4] + bv, 0.f), v5 = fmaxf(acc[j][5] + bv, 0.f);
        float v6 = fmaxf(acc[j][6] + bv, 0.f), v7 = fmaxf(acc[j][7] + bv, 0.f);
        if (xbase + 7 < W_) {
            ((float4*)orow)[0] = make_float4(v0, v1, v2, v3);
            ((float4*)orow)[1] = make_float4(v4, v5, v6, v7);
        } else {
            float vv[8] = {v0, v1, v2, v3, v4, v5, v6, v7};
            for (int i = 0; i < 8; i++)
                if (xbase + i < W_) orow[i] = vv[i];
        }
    }
}

// ---- 1x1 cls conv -> conf[p*9+a], fused radix histogram pass 1 ----
__global__ __launch_bounds__(256) void k_cls(const float* __restrict__ x,
                                             const float* __restrict__ wcr,
                                             const float* __restrict__ bc,
                                             float* __restrict__ conf,
                                             unsigned* __restrict__ hist) {
    int p = blockIdx.x * 256 + threadIdx.x;
    if (p >= HW) return;
    float acc[9];
#pragma unroll
    for (int a = 0; a < 9; a++) acc[a] = 0.f;
    for (int c = 0; c < 256; c++) {
        float xv = x[c * HW + p];
        const float* wp = wcr + c * 9;  // uniform -> s_load
#pragma unroll
        for (int a = 0; a < 9; a++) acc[a] = fmaf(wp[a], xv, acc[a]);
    }
#pragma unroll
    for (int a = 0; a < 9; a++) {
        float v = acc[a] + bc[a];
        conf[p * 9 + a] = v;
        atomicAdd(&hist[fkey(v) >> 16], 1u);
    }
}

__global__ __launch_bounds__(256) void k_hist2(const float* __restrict__ conf,
                                               const unsigned* __restrict__ scal, unsigned* hist) {
    int n = blockIdx.x * 256 + threadIdx.x;
    if (n >= NANCH) return;
    unsigned key = fkey(conf[n]);
    if ((key >> 16) == scal[0]) atomicAdd(&hist[key & 0xFFFFu], 1u);
}

// ---- descending scan of 65536-bin histogram, find bin of the target-th largest ----
__global__ __launch_bounds__(1024) void k_scan(const unsigned* __restrict__ hist,
                                               unsigned* scal, int mode) {
    __shared__ unsigned ssum[1024];
    int t = threadIdx.x;
    unsigned target = 6000u - (mode ? scal[1] : 0u);
    int base = 65535 - t * 64;
    unsigned s = 0;
    for (int k = 0; k < 64; k++) s += hist[base - k];
    ssum[t] = s;
    __syncthreads();
    for (int off = 1; off < 1024; off <<= 1) {
        unsigned v = (t >= off) ? ssum[t - off] : 0u;
        __syncthreads();
        ssum[t] += v;
        __syncthreads();
    }
    unsigned incl = ssum[t], excl = incl - s;
    if (excl < target && target <= incl) {
        unsigned run = excl;
        for (int k = 0; k < 64; k++) {
            unsigned c = hist[base - k];
            if (run + c >= target) { scal[2 * mode] = (unsigned)(base - k); scal[2 * mode + 1] = run; break; }
            run += c;
        }
    }
}

// ---- gather all keys >= threshold (ties after strict-greater block) ----
__global__ __launch_bounds__(256) void k_gather(const float* __restrict__ conf,
                                                unsigned* scal, unsigned long long* sel) {
    int n = blockIdx.x * 256 + threadIdx.x;
    if (n >= NANCH) return;
    unsigned B1 = scal[0], cnt1 = scal[1], B2 = scal[2], cnt2 = scal[3];
    unsigned T = (B1 << 16) | B2;
    unsigned key = fkey(conf[n]);
    if (key < T) return;
    unsigned long long kk = ((unsigned long long)(~key) << 32) | (unsigned)n;  // asc sort => score desc, idx asc
    if (key > T) {
        unsigned pos = atomicAdd(&scal[4], 1u);
        if (pos < 8192u) sel[pos] = kk;
    } else {
        unsigned pos = cnt1 + cnt2 + atomicAdd(&scal[5], 1u);
        if (pos < 8192u) sel[pos] = kk;
    }
}

// ---- one-block bitonic sort of 8192 keys, emit top-6000 indices ----
__global__ __launch_bounds__(1024) void k_sort(const unsigned* __restrict__ scal,
                                               const unsigned long long* __restrict__ sel,
                                               unsigned* __restrict__ topidx) {
    __shared__ unsigned long long sk[8192];
    unsigned G = scal[1] + scal[3];
    unsigned filled = G + scal[5];
    if (filled > 8192u) filled = 8192u;
    for (int i = threadIdx.x; i < 8192; i += 1024)
        sk[i] = (i < (int)filled) ? sel[i] : 0xFFFFFFFFFFFFFFFFull;
    __syncthreads();
    for (int k = 2; k <= 8192; k <<= 1) {
        for (int j = k >> 1; j > 0; j >>= 1) {
            for (int i = threadIdx.x; i < 8192; i += 1024) {
                int l = i ^ j;
                if (l > i) {
                    unsigned long long a = sk[i], b = sk[l];
                    bool up = ((i & k) == 0);
                    if ((a > b) == up) { sk[i] = b; sk[l] = a; }
                }
            }
            __syncthreads();
        }
    }
    for (int r = threadIdx.x; r < PRE_N; r += 1024)
        topidx[r] = (unsigned)(sk[r] & 0xFFFFFFFFull);
}

// ---- per-proposal: reg conv (4 channels), anchor, decode, clip, valid ----
__global__ __launch_bounds__(64) void k_prop(const float* __restrict__ x,
                                             const float* __restrict__ wreg,
                                             const float* __restrict__ breg,
                                             const unsigned* __restrict__ topidx,
                                             const int* __restrict__ imh, const int* __restrict__ imw,
                                             float* __restrict__ boxes, int* __restrict__ valid) {
    int r = blockIdx.x;
    int lane = threadIdx.x;
    unsigned n = topidx[r];
    int a = (int)(n % 9u); int p = (int)(n / 9u);
    const float* wr = wreg + (4 * a) * 256;
    float s0 = 0, s1 = 0, s2 = 0, s3 = 0;
    for (int c = lane; c < 256; c += 64) {
        float xv = x[c * HW + p];
        s0 = fmaf(wr[c], xv, s0);
        s1 = fmaf(wr[256 + c], xv, s1);
        s2 = fmaf(wr[512 + c], xv, s2);
        s3 = fmaf(wr[768 + c], xv, s3);
    }
#pragma unroll
    for (int off = 32; off >= 1; off >>= 1) {
        s0 += __shfl_down(s0, off);
        s1 += __shfl_down(s1, off);
        s2 += __shfl_down(s2, off);
        s3 += __shfl_down(s3, off);
    }
    if (lane == 0) {
        float dx = s0 + breg[4 * a], dy = s1 + breg[4 * a + 1];
        float dw = s2 + breg[4 * a + 2], dh = s3 + breg[4 * a + 3];
        int wi = p % W_, hi = p / W_;
        const double SC[3] = {32.0, 64.0, 128.0};
        const double RT[3] = {0.5, 1.0, 2.0};
        double sd = SC[a / 3], rd = RT[a % 3];
        double wb = sd * sqrt(1.0 / rd), hb = sd * sqrt(rd);
        float bx1 = (float)(-wb * 0.5), by1 = (float)(-hb * 0.5);
        float bx2 = (float)(wb * 0.5),  by2 = (float)(hb * 0.5);
        float cxs = ((float)wi + 0.5f) * 4.0f, cys = ((float)hi + 0.5f) * 4.0f;
        float x1a = cxs + bx1, y1a = cys + by1, x2a = cxs + bx2, y2a = cys + by2;
        float wa = x2a - x1a, ha = y2a - y1a;
        float cxa = x1a + 0.5f * wa, cya = y1a + 0.5f * ha;
        float cx = dx * wa + cxa, cy = dy * ha + cya;
        float ww = expf(dw) * wa, hh = expf(dh) * ha;
        float X1 = cx - 0.5f * ww, Y1 = cy - 0.5f * hh;
        float X2 = cx + 0.5f * ww, Y2 = cy + 0.5f * hh;
        float Wf = (float)(*imw), Hf = (float)(*imh);
        X1 = fminf(fmaxf(X1, 0.f), Wf); Y1 = fminf(fmaxf(Y1, 0.f), Hf);
        X2 = fminf(fmaxf(X2, 0.f), Wf); Y2 = fminf(fmaxf(Y2, 0.f), Hf);
        boxes[4 * r] = X1; boxes[4 * r + 1] = Y1; boxes[4 * r + 2] = X2; boxes[4 * r + 3] = Y2;
        valid[r] = ((X2 - X1) >= 1.0f && (Y2 - Y1) >= 1.0f) ? 1 : 0;
    }
}

// ---- NMS IoU bitmask: mask[i][jw] bit b = (j=jw*64+b > i) && iou>0.7 ----
__global__ __launch_bounds__(256) void k_mask(const float* __restrict__ boxes,
                                              unsigned long long* __restrict__ mask) {
    __shared__ float jb[256];
    int jw = blockIdx.x;
    int i = blockIdx.y * 256 + threadIdx.x;
    {
        int idx = jw * 256 + threadIdx.x;
        jb[threadIdx.x] = (idx < PRE_N * 4) ? boxes[idx] : 0.f;
    }
    __syncthreads();
    if (i >= PRE_N) return;
    float ax1 = boxes[4 * i], ay1 = boxes[4 * i + 1], ax2 = boxes[4 * i + 2], ay2 = boxes[4 * i + 3];
    float aarea = (ax2 - ax1) * (ay2 - ay1);
    unsigned long long m = 0;
    int jbase = jw * 64;
    for (int b = 0; b < 64; b++) {
        int j = jbase + b;
        if (j <= i || j >= PRE_N) continue;
        float bx1 = jb[4 * b], by1 = jb[4 * b + 1], bx2 = jb[4 * b + 2], by2 = jb[4 * b + 3];
        float barea = (bx2 - bx1) * (by2 - by1);
        float xx1 = fmaxf(ax1, bx1), yy1 = fmaxf(ay1, by1);
        float xx2 = fminf(ax2, bx2), yy2 = fminf(ay2, by2);
        float w = fmaxf(xx2 - xx1, 0.f), h = fmaxf(yy2 - yy1, 0.f);
        float inter = w * h;
        float iou = inter / (aarea + barea - inter + 1e-9f);
        if (iou > 0.7f) m |= (1ull << b);
    }
    mask[(size_t)i * NWORDS + jw] = m;
}

// ---- greedy scan: serial part iterates only candidate bits ----
__global__ __launch_bounds__(128) void k_scan_nms(const unsigned long long* __restrict__ mask,
                                                  const int* __restrict__ valid,
                                                  const float* __restrict__ boxes,
                                                  float* __restrict__ out) {
    __shared__ unsigned long long removed[NWORDS];
    __shared__ unsigned long long validw[NWORDS];
    __shared__ unsigned long long curm[64];
    __shared__ int keepList[POST_N];
    __shared__ int cnt;
    __shared__ unsigned long long keptbits;
    int t = threadIdx.x;
    if (t < NWORDS) { removed[t] = 0ull; validw[t] = 0ull; }
    if (t == 0) cnt = 0;
    __syncthreads();
    for (int i = t; i < PRE_N; i += 128)
        if (valid[i]) atomicOr(&validw[i >> 6], 1ull << (i & 63));
    __syncthreads();
    for (int w = 0; w < NWORDS; w++) {
        unsigned long long candw = validw[w] & ~removed[w];  // uniform (LDS, post-sync)
        if (!candw) continue;
        if (t < 64) curm[t] = ((candw >> t) & 1ull) ? mask[(size_t)(w * 64 + t) * NWORDS + w] : 0ull;
        __syncthreads();
        if (t == 0) {
            unsigned long long cand = candw;
            unsigned long long kb = 0ull;
            int c = cnt;
            while (cand && c < POST_N) {
                int b = __ffsll((unsigned long long)cand) - 1;
                keepList[c++] = w * 64 + b;
                kb |= 1ull << b;
                cand &= ~(1ull << b);
                cand &= ~curm[b];
            }
            cnt = c; keptbits = kb;
        }
        __syncthreads();
        if (cnt >= POST_N) break;
        unsigned long long kb = keptbits;
        if (kb) {
            for (int w2 = w + 1 + t; w2 < NWORDS; w2 += 128) {
                unsigned long long acc2 = removed[w2];
                unsigned long long tt = kb;
                while (tt) {
                    int b = __ffsll((unsigned long long)tt) - 1;
                    tt &= tt - 1;
                    acc2 |= mask[(size_t)(w * 64 + b) * NWORDS + w2];
                }
                removed[w2] = acc2;
            }
        }
        __syncthreads();
    }
    __syncthreads();
    int c = cnt;
    for (int e = t; e < POST_N * 4; e += 128) {
        int r = e >> 2;
        out[e] = (r < c) ? boxes[4 * keepList[r] + (e & 3)] : 0.f;
    }
}

extern "C" void kernel_launch(void* const* d_in, const int* in_sizes, int n_in,
                              void* d_out, int out_size, void* d_ws, size_t ws_size,
                              hipStream_t stream) {
    const float* feature = (const float*)d_in[0];
    const float* w1   = (const float*)d_in[1];
    const float* b1   = (const float*)d_in[2];
    const float* wcls = (const float*)d_in[3];
    const float* bcls = (const float*)d_in[4];
    const float* wreg = (const float*)d_in[5];
    const float* breg = (const float*)d_in[6];
    const int* imh = (const int*)d_in[7];
    const int* imw = (const int*)d_in[8];

    char* ws = (char*)d_ws;
    float* xbuf  = (float*)(ws + X_OFF);
    float* conf  = (float*)(ws + CONF_OFF);
    unsigned* hist1 = (unsigned*)(ws + HIST1_OFF);
    unsigned* hist2 = (unsigned*)(ws + HIST2_OFF);
    unsigned* scal  = (unsigned*)(ws + SCAL_OFF);
    unsigned long long* sel = (unsigned long long*)(ws + SEL_OFF);
    unsigned* topidx = (unsigned*)(ws + TOPIDX_OFF);
    float* boxes = (float*)(ws + BOXES_OFF);
    int* valid   = (int*)(ws + VALID_OFF);
    unsigned long long* mask = (unsigned long long*)(ws + MASK_OFF);
    float* w1r = (float*)(ws + W1R_OFF);
    float* wcr = (float*)(ws + WCR_OFF);
    float* outF = (float*)d_out;

    hipLaunchKernelGGL(k_init,   dim3(2826), dim3(256), 0, stream, w1, wcls, hist1, w1r, wcr);
    hipLaunchKernelGGL(k_conv1,  dim3(9, 25, 4), dim3(256), 0, stream, feature, w1r, b1, xbuf);
    hipLaunchKernelGGL(k_cls,    dim3(213),  dim3(256), 0, stream, xbuf, wcr, bcls, conf, hist1);
    hipLaunchKernelGGL(k_scan,   dim3(1),    dim3(1024), 0, stream, hist1, scal, 0);
    hipLaunchKernelGGL(k_hist2,  dim3(1913), dim3(256), 0, stream, conf, scal, hist2);
    hipLaunchKernelGGL(k_scan,   dim3(1),    dim3(1024), 0, stream, hist2, scal, 1);
    hipLaunchKernelGGL(k_gather, dim3(1913), dim3(256), 0, stream, conf, scal, sel);
    hipLaunchKernelGGL(k_sort,   dim3(1),    dim3(1024), 0, stream, scal, sel, topidx);
    hipLaunchKernelGGL(k_prop,   dim3(PRE_N), dim3(64), 0, stream, xbuf, wreg, breg, topidx, imh, imw, boxes, valid);
    hipLaunchKernelGGL(k_mask,   dim3(NWORDS, 24), dim3(256), 0, stream, boxes, mask);
    hipLaunchKernelGGL(k_scan_nms, dim3(1), dim3(128), 0, stream, mask, valid, boxes, outF);
}

// Round 4
// 1813.100 us; speedup vs baseline: 1.1242x; 1.0088x over previous
//
#include <hip/hip_runtime.h>
#include <hip/hip_bf16.h>
#include <math.h>

#define H_ 200
#define W_ 272
#define C_ 256
#define HW 54400
#define NANCH 489600
#define PRE_N 6000
#define POST_N 1000
#define NWORDS 94   // ceil(6000/64)

// ---- workspace layout (bytes) ----
#define X_OFF       0ull                 // 256*54400*4 = 55,705,600
#define CONF_OFF    55705600ull          // 489600*4   =  1,958,400
#define HIST1_OFF   57664000ull          // 65536*4    =    262,144
#define HIST2_OFF   57926144ull          // 65536*4    =    262,144
#define SCAL_OFF    58188288ull          // 64*4
#define SEL_OFF     58188544ull          // 8192*8     =     65,536
#define TOPIDX_OFF  58254080ull          // 6000*4
#define BOXES_OFF   58278080ull          // 6000*4*4
#define VALID_OFF   58374080ull          // 6000*4
#define MASK_OFF    58398080ull          // 6000*94*8  =  4,512,000
#define W1R_OFF     62910080ull          // [32][256][9][8]*4 = 2,359,296
#define WCR_OFF     65269376ull          // 9*256*4

typedef float v2f __attribute__((ext_vector_type(2)));

__device__ __forceinline__ unsigned fkey(float fv) {
    unsigned u = __float_as_uint(fv);
    return (u & 0x80000000u) ? ~u : (u | 0x80000000u);  // monotone: bigger float -> bigger key
}

// ---- clear histograms + repack weights, one launch ----
// w1r layout: [wg=oc>>3][ic][k][oc&7] -> per-wave (ic,k) weights are 8 contiguous
// floats, wave-uniform address -> s_load into SGPRs.
__global__ __launch_bounds__(256) void k_init(const float* __restrict__ w1,
                                              const float* __restrict__ wcls,
                                              unsigned* __restrict__ hist1,
                                              float* __restrict__ w1r,
                                              float* __restrict__ wcr) {
    int e = blockIdx.x * 256 + threadIdx.x;
    if (e < 131136) hist1[e] = 0u;
    int e1 = e - 131136;
    if (e1 >= 0 && e1 < 589824) {
        int oc = e1 / 2304; int rem = e1 % 2304; int ic = rem / 9; int k = rem % 9;
        int wg = oc >> 3, o = oc & 7;
        w1r[(((size_t)wg * 256 + ic) * 9 + k) * 8 + o] = w1[e1];
    } else if (e1 >= 589824 && e1 < 589824 + 2304) {
        int e2 = e1 - 589824; int a = e2 / 256; int c = e2 % 256;
        wcr[c * 9 + a] = wcls[e2];
    }
}

// ---- 3x3 conv + bias + relu. SGPR-weight implicit GEMM. ----
// Block: 32x * 16y spatial, 4 waves x 8oc = 32 oc. Thread: 8x * 8oc.
// Weights: wave-uniform s_load (no LDS, no VALU cost). Input: LDS stride-35
// rows -> b32 reads with <=2-way bank aliasing (free). FMA order ic->ky->kx
// per accumulator == previous rounds (bitwise-stable scores).
__global__ __launch_bounds__(256) void k_conv1(const float* __restrict__ f,
                                               const float* __restrict__ w1r,
                                               const float* __restrict__ b1,
                                               float* __restrict__ xo) {
    __shared__ float sI[8 * 18 * 35];   // 20,160 B
    int tid = threadIdx.x;
    int lane = tid & 63;
    int wgl  = __builtin_amdgcn_readfirstlane(tid >> 6);  // wave id 0..3 (uniform)
    int xg = lane & 3;            // 4 x-subtiles of 8
    int yg = lane >> 2;           // 16 rows
    int X0 = blockIdx.x * 32;
    int Y0 = blockIdx.y * 16;
    int wg = blockIdx.z * 4 + wgl;   // oc-group of 8 (0..31), wave-uniform
    int y = Y0 + yg;
    int xbase = X0 + xg * 8;

    v2f acc2[4][8];               // [oc-pair][x] = 64 VGPRs
#pragma unroll
    for (int o2 = 0; o2 < 4; o2++)
#pragma unroll
        for (int i = 0; i < 8; i++) acc2[o2][i] = (v2f){0.f, 0.f};

    const float* wbase = w1r + ((size_t)wg * 256) * 9 * 8;

    for (int ic0 = 0; ic0 < 256; ic0 += 8) {
        __syncthreads();
        // stage input halo tile: 8 ic x 18 rows x 34 cols (stride 35)
        for (int l = tid; l < 4896; l += 256) {
            int ci = l / 612; int r = l - ci * 612; int ry = r / 34; int rx = r - ry * 34;
            int gx = X0 - 1 + rx, gy = Y0 - 1 + ry;
            float v = 0.f;
            if (gx >= 0 && gx < W_ && gy >= 0 && gy < H_)
                v = f[(ic0 + ci) * HW + gy * W_ + gx];
            sI[(ci * 18 + ry) * 35 + rx] = v;
        }
        __syncthreads();
        for (int ci = 0; ci < 8; ci++) {
            const float* wp = wbase + ((size_t)(ic0 + ci) * 9) * 8;  // 72 floats [ky][kx][8]
#pragma unroll
            for (int ky = 0; ky < 3; ky++) {
                const float* irow = &sI[(ci * 18 + yg + ky) * 35 + xg * 8];
                float in[10];
#pragma unroll
                for (int j = 0; j < 10; j++) in[j] = irow[j];
                const float* wrow = wp + ky * 24;   // [kx][8]
#pragma unroll
                for (int kx = 0; kx < 3; kx++) {
#pragma unroll
                    for (int o2 = 0; o2 < 4; o2++) {
                        v2f w2 = {wrow[kx * 8 + 2 * o2], wrow[kx * 8 + 2 * o2 + 1]};
#pragma unroll
                        for (int i = 0; i < 8; i++) {
                            v2f iv = {in[i + kx], in[i + kx]};
                            acc2[o2][i] = __builtin_elementwise_fma(w2, iv, acc2[o2][i]);
                        }
                    }
                }
            }
        }
    }
    // epilogue: bias + relu + store. y may exceed 199 (last y-block), x may exceed 271.
    if (y < H_) {
#pragma unroll
        for (int o2 = 0; o2 < 4; o2++) {
#pragma unroll
            for (int h = 0; h < 2; h++) {
                int oc = wg * 8 + 2 * o2 + h;
                float bv = b1[oc];
                float* orow = xo + (size_t)oc * HW + y * W_ + xbase;
                float v0 = fmaxf(acc2[o2][0][h] + bv, 0.f), v1 = fmaxf(acc2[o2][1][h] + bv, 0.f);
                float v2 = fmaxf(acc2[o2][2][h] + bv, 0.f), v3 = fmaxf(acc2[o2][3][h] + bv, 0.f);
                float v4 = fmaxf(acc2[o2][4][h] + bv, 0.f), v5 = fmaxf(acc2[o2][5][h] + bv, 0.f);
                float v6 = fmaxf(acc2[o2][6][h] + bv, 0.f), v7 = fmaxf(acc2[o2][7][h] + bv, 0.f);
                if (xbase + 7 < W_) {
                    ((float4*)orow)[0] = make_float4(v0, v1, v2, v3);
                    ((float4*)orow)[1] = make_float4(v4, v5, v6, v7);
                } else {
                    float vv[8] = {v0, v1, v2, v3, v4, v5, v6, v7};
                    for (int i = 0; i < 8; i++)
                        if (xbase + i < W_) orow[i] = vv[i];
                }
            }
        }
    }
}

// ---- 1x1 cls conv -> conf[p*9+a], fused radix histogram pass 1 ----
__global__ __launch_bounds__(256) void k_cls(const float* __restrict__ x,
                                             const float* __restrict__ wcr,
                                             const float* __restrict__ bc,
                                             float* __restrict__ conf,
                                             unsigned* __restrict__ hist) {
    int p = blockIdx.x * 256 + threadIdx.x;
    if (p >= HW) return;
    float acc[9];
#pragma unroll
    for (int a = 0; a < 9; a++) acc[a] = 0.f;
    for (int c = 0; c < 256; c++) {
        float xv = x[c * HW + p];
        const float* wp = wcr + c * 9;  // uniform -> s_load
#pragma unroll
        for (int a = 0; a < 9; a++) acc[a] = fmaf(wp[a], xv, acc[a]);
    }
#pragma unroll
    for (int a = 0; a < 9; a++) {
        float v = acc[a] + bc[a];
        conf[p * 9 + a] = v;
        atomicAdd(&hist[fkey(v) >> 16], 1u);
    }
}

__global__ __launch_bounds__(256) void k_hist2(const float* __restrict__ conf,
                                               const unsigned* __restrict__ scal, unsigned* hist) {
    int n = blockIdx.x * 256 + threadIdx.x;
    if (n >= NANCH) return;
    unsigned key = fkey(conf[n]);
    if ((key >> 16) == scal[0]) atomicAdd(&hist[key & 0xFFFFu], 1u);
}

// ---- descending scan of 65536-bin histogram, find bin of the target-th largest ----
__global__ __launch_bounds__(1024) void k_scan(const unsigned* __restrict__ hist,
                                               unsigned* scal, int mode) {
    __shared__ unsigned ssum[1024];
    int t = threadIdx.x;
    unsigned target = 6000u - (mode ? scal[1] : 0u);
    int base = 65535 - t * 64;
    unsigned s = 0;
    for (int k = 0; k < 64; k++) s += hist[base - k];
    ssum[t] = s;
    __syncthreads();
    for (int off = 1; off < 1024; off <<= 1) {
        unsigned v = (t >= off) ? ssum[t - off] : 0u;
        __syncthreads();
        ssum[t] += v;
        __syncthreads();
    }
    unsigned incl = ssum[t], excl = incl - s;
    if (excl < target && target <= incl) {
        unsigned run = excl;
        for (int k = 0; k < 64; k++) {
            unsigned c = hist[base - k];
            if (run + c >= target) { scal[2 * mode] = (unsigned)(base - k); scal[2 * mode + 1] = run; break; }
            run += c;
        }
    }
}

// ---- gather all keys >= threshold (ties after strict-greater block) ----
__global__ __launch_bounds__(256) void k_gather(const float* __restrict__ conf,
                                                unsigned* scal, unsigned long long* sel) {
    int n = blockIdx.x * 256 + threadIdx.x;
    if (n >= NANCH) return;
    unsigned B1 = scal[0], cnt1 = scal[1], B2 = scal[2], cnt2 = scal[3];
    unsigned T = (B1 << 16) | B2;
    unsigned key = fkey(conf[n]);
    if (key < T) return;
    unsigned long long kk = ((unsigned long long)(~key) << 32) | (unsigned)n;  // asc sort => score desc, idx asc
    if (key > T) {
        unsigned pos = atomicAdd(&scal[4], 1u);
        if (pos < 8192u) sel[pos] = kk;
    } else {
        unsigned pos = cnt1 + cnt2 + atomicAdd(&scal[5], 1u);
        if (pos < 8192u) sel[pos] = kk;
    }
}

// ---- one-block bitonic sort of 8192 keys, emit top-6000 indices ----
__global__ __launch_bounds__(1024) void k_sort(const unsigned* __restrict__ scal,
                                               const unsigned long long* __restrict__ sel,
                                               unsigned* __restrict__ topidx) {
    __shared__ unsigned long long sk[8192];
    unsigned G = scal[1] + scal[3];
    unsigned filled = G + scal[5];
    if (filled > 8192u) filled = 8192u;
    for (int i = threadIdx.x; i < 8192; i += 1024)
        sk[i] = (i < (int)filled) ? sel[i] : 0xFFFFFFFFFFFFFFFFull;
    __syncthreads();
    for (int k = 2; k <= 8192; k <<= 1) {
        for (int j = k >> 1; j > 0; j >>= 1) {
            for (int i = threadIdx.x; i < 8192; i += 1024) {
                int l = i ^ j;
                if (l > i) {
                    unsigned long long a = sk[i], b = sk[l];
                    bool up = ((i & k) == 0);
                    if ((a > b) == up) { sk[i] = b; sk[l] = a; }
                }
            }
            __syncthreads();
        }
    }
    for (int r = threadIdx.x; r < PRE_N; r += 1024)
        topidx[r] = (unsigned)(sk[r] & 0xFFFFFFFFull);
}

// ---- per-proposal: reg conv (4 channels), anchor, decode, clip, valid ----
__global__ __launch_bounds__(64) void k_prop(const float* __restrict__ x,
                                             const float* __restrict__ wreg,
                                             const float* __restrict__ breg,
                                             const unsigned* __restrict__ topidx,
                                             const int* __restrict__ imh, const int* __restrict__ imw,
                                             float* __restrict__ boxes, int* __restrict__ valid) {
    int r = blockIdx.x;
    int lane = threadIdx.x;
    unsigned n = topidx[r];
    int a = (int)(n % 9u); int p = (int)(n / 9u);
    const float* wr = wreg + (4 * a) * 256;
    float s0 = 0, s1 = 0, s2 = 0, s3 = 0;
    for (int c = lane; c < 256; c += 64) {
        float xv = x[c * HW + p];
        s0 = fmaf(wr[c], xv, s0);
        s1 = fmaf(wr[256 + c], xv, s1);
        s2 = fmaf(wr[512 + c], xv, s2);
        s3 = fmaf(wr[768 + c], xv, s3);
    }
#pragma unroll
    for (int off = 32; off >= 1; off >>= 1) {
        s0 += __shfl_down(s0, off);
        s1 += __shfl_down(s1, off);
        s2 += __shfl_down(s2, off);
        s3 += __shfl_down(s3, off);
    }
    if (lane == 0) {
        float dx = s0 + breg[4 * a], dy = s1 + breg[4 * a + 1];
        float dw = s2 + breg[4 * a + 2], dh = s3 + breg[4 * a + 3];
        int wi = p % W_, hi = p / W_;
        const double SC[3] = {32.0, 64.0, 128.0};
        const double RT[3] = {0.5, 1.0, 2.0};
        double sd = SC[a / 3], rd = RT[a % 3];
        double wb = sd * sqrt(1.0 / rd), hb = sd * sqrt(rd);
        float bx1 = (float)(-wb * 0.5), by1 = (float)(-hb * 0.5);
        float bx2 = (float)(wb * 0.5),  by2 = (float)(hb * 0.5);
        float cxs = ((float)wi + 0.5f) * 4.0f, cys = ((float)hi + 0.5f) * 4.0f;
        float x1a = cxs + bx1, y1a = cys + by1, x2a = cxs + bx2, y2a = cys + by2;
        float wa = x2a - x1a, ha = y2a - y1a;
        float cxa = x1a + 0.5f * wa, cya = y1a + 0.5f * ha;
        float cx = dx * wa + cxa, cy = dy * ha + cya;
        float ww = expf(dw) * wa, hh = expf(dh) * ha;
        float X1 = cx - 0.5f * ww, Y1 = cy - 0.5f * hh;
        float X2 = cx + 0.5f * ww, Y2 = cy + 0.5f * hh;
        float Wf = (float)(*imw), Hf = (float)(*imh);
        X1 = fminf(fmaxf(X1, 0.f), Wf); Y1 = fminf(fmaxf(Y1, 0.f), Hf);
        X2 = fminf(fmaxf(X2, 0.f), Wf); Y2 = fminf(fmaxf(Y2, 0.f), Hf);
        boxes[4 * r] = X1; boxes[4 * r + 1] = Y1; boxes[4 * r + 2] = X2; boxes[4 * r + 3] = Y2;
        valid[r] = ((X2 - X1) >= 1.0f && (Y2 - Y1) >= 1.0f) ? 1 : 0;
    }
}

// ---- NMS IoU bitmask: mask[i][jw] bit b = (j=jw*64+b > i) && iou>0.7 ----
__global__ __launch_bounds__(256) void k_mask(const float* __restrict__ boxes,
                                              unsigned long long* __restrict__ mask) {
    __shared__ float jb[256];
    int jw = blockIdx.x;
    int i = blockIdx.y * 256 + threadIdx.x;
    {
        int idx = jw * 256 + threadIdx.x;
        jb[threadIdx.x] = (idx < PRE_N * 4) ? boxes[idx] : 0.f;
    }
    __syncthreads();
    if (i >= PRE_N) return;
    float ax1 = boxes[4 * i], ay1 = boxes[4 * i + 1], ax2 = boxes[4 * i + 2], ay2 = boxes[4 * i + 3];
    float aarea = (ax2 - ax1) * (ay2 - ay1);
    unsigned long long m = 0;
    int jbase = jw * 64;
    for (int b = 0; b < 64; b++) {
        int j = jbase + b;
        if (j <= i || j >= PRE_N) continue;
        float bx1 = jb[4 * b], by1 = jb[4 * b + 1], bx2 = jb[4 * b + 2], by2 = jb[4 * b + 3];
        float barea = (bx2 - bx1) * (by2 - by1);
        float xx1 = fmaxf(ax1, bx1), yy1 = fmaxf(ay1, by1);
        float xx2 = fminf(ax2, bx2), yy2 = fminf(ay2, by2);
        float w = fmaxf(xx2 - xx1, 0.f), h = fmaxf(yy2 - yy1, 0.f);
        float inter = w * h;
        float iou = inter / (aarea + barea - inter + 1e-9f);
        if (iou > 0.7f) m |= (1ull << b);
    }
    mask[(size_t)i * NWORDS + jw] = m;
}

// ---- greedy scan: diagonal masks preloaded to LDS; serial part iterates kept bits ----
__global__ __launch_bounds__(128) void k_scan_nms(const unsigned long long* __restrict__ mask,
                                                  const int* __restrict__ valid,
                                                  const float* __restrict__ boxes,
                                                  float* __restrict__ out) {
    __shared__ unsigned long long diag[NWORDS][64];   // 48,128 B
    __shared__ unsigned long long removed[NWORDS];
    __shared__ unsigned long long validw[NWORDS];
    __shared__ int keepList[POST_N];
    __shared__ int cnt;
    __shared__ unsigned long long keptbits;
    int t = threadIdx.x;
    if (t < NWORDS) { removed[t] = 0ull; validw[t] = 0ull; }
    if (t == 0) cnt = 0;
    __syncthreads();
    for (int l = t; l < NWORDS * 64; l += 128) {
        int w = l >> 6, b = l & 63;
        int i = w * 64 + b;
        diag[w][b] = (i < PRE_N) ? mask[(size_t)i * NWORDS + w] : 0ull;
    }
    for (int i = t; i < PRE_N; i += 128)
        if (valid[i]) atomicOr(&validw[i >> 6], 1ull << (i & 63));
    __syncthreads();
    for (int w = 0; w < NWORDS; w++) {
        unsigned long long candw = validw[w] & ~removed[w];  // uniform (LDS, post-sync)
        if (!candw) continue;
        if (t == 0) {
            unsigned long long cand = candw;
            unsigned long long kb = 0ull;
            int c = cnt;
            while (cand && c < POST_N) {
                int b = __ffsll((unsigned long long)cand) - 1;
                keepList[c++] = w * 64 + b;
                kb |= 1ull << b;
                cand &= ~(1ull << b);
                cand &= ~diag[w][b];
            }
            cnt = c; keptbits = kb;
        }
        __syncthreads();
        if (cnt >= POST_N) break;
        unsigned long long kb = keptbits;
        if (kb) {
            for (int w2 = w + 1 + t; w2 < NWORDS; w2 += 128) {
                unsigned long long acc2 = removed[w2];
                unsigned long long tt = kb;
                while (tt) {
                    int b = __ffsll((unsigned long long)tt) - 1;
                    tt &= tt - 1;
                    acc2 |= mask[(size_t)(w * 64 + b) * NWORDS + w2];
                }
                removed[w2] = acc2;
            }
        }
        __syncthreads();
    }
    __syncthreads();
    int c = cnt;
    for (int e = t; e < POST_N * 4; e += 128) {
        int r = e >> 2;
        out[e] = (r < c) ? boxes[4 * keepList[r] + (e & 3)] : 0.f;
    }
}

extern "C" void kernel_launch(void* const* d_in, const int* in_sizes, int n_in,
                              void* d_out, int out_size, void* d_ws, size_t ws_size,
                              hipStream_t stream) {
    const float* feature = (const float*)d_in[0];
    const float* w1   = (const float*)d_in[1];
    const float* b1   = (const float*)d_in[2];
    const float* wcls = (const float*)d_in[3];
    const float* bcls = (const float*)d_in[4];
    const float* wreg = (const float*)d_in[5];
    const float* breg = (const float*)d_in[6];
    const int* imh = (const int*)d_in[7];
    const int* imw = (const int*)d_in[8];

    char* ws = (char*)d_ws;
    float* xbuf  = (float*)(ws + X_OFF);
    float* conf  = (float*)(ws + CONF_OFF);
    unsigned* hist1 = (unsigned*)(ws + HIST1_OFF);
    unsigned* hist2 = (unsigned*)(ws + HIST2_OFF);
    unsigned* scal  = (unsigned*)(ws + SCAL_OFF);
    unsigned long long* sel = (unsigned long long*)(ws + SEL_OFF);
    unsigned* topidx = (unsigned*)(ws + TOPIDX_OFF);
    float* boxes = (float*)(ws + BOXES_OFF);
    int* valid   = (int*)(ws + VALID_OFF);
    unsigned long long* mask = (unsigned long long*)(ws + MASK_OFF);
    float* w1r = (float*)(ws + W1R_OFF);
    float* wcr = (float*)(ws + WCR_OFF);
    float* outF = (float*)d_out;

    hipLaunchKernelGGL(k_init,   dim3(2826), dim3(256), 0, stream, w1, wcls, hist1, w1r, wcr);
    hipLaunchKernelGGL(k_conv1,  dim3(9, 13, 8), dim3(256), 0, stream, feature, w1r, b1, xbuf);
    hipLaunchKernelGGL(k_cls,    dim3(213),  dim3(256), 0, stream, xbuf, wcr, bcls, conf, hist1);
    hipLaunchKernelGGL(k_scan,   dim3(1),    dim3(1024), 0, stream, hist1, scal, 0);
    hipLaunchKernelGGL(k_hist2,  dim3(1913), dim3(256), 0, stream, conf, scal, hist2);
    hipLaunchKernelGGL(k_scan,   dim3(1),    dim3(1024), 0, stream, hist2, scal, 1);
    hipLaunchKernelGGL(k_gather, dim3(1913), dim3(256), 0, stream, conf, scal, sel);
    hipLaunchKernelGGL(k_sort,   dim3(1),    dim3(1024), 0, stream, scal, sel, topidx);
    hipLaunchKernelGGL(k_prop,   dim3(PRE_N), dim3(64), 0, stream, xbuf, wreg, breg, topidx, imh, imw, boxes, valid);
    hipLaunchKernelGGL(k_mask,   dim3(NWORDS, 24), dim3(256), 0, stream, boxes, mask);
    hipLaunchKernelGGL(k_scan_nms, dim3(1), dim3(128), 0, stream, mask, valid, boxes, outF);
}

// Round 5
// 1793.091 us; speedup vs baseline: 1.1367x; 1.0112x over previous
//
#include <hip/hip_runtime.h>
#include <hip/hip_bf16.h>
#include <math.h>

#define H_ 200
#define W_ 272
#define C_ 256
#define HW 54400
#define NANCH 489600
#define PRE_N 6000
#define POST_N 1000
#define NWORDS 94   // ceil(6000/64)
#define CHUNK_W 2720  // 8 ic * 10 rows * 34 cols halo

// ---- workspace layout (bytes) ----
#define X_OFF       0ull                 // 256*54400*4 = 55,705,600
#define CONF_OFF    55705600ull          // 489600*4   =  1,958,400
#define HIST1_OFF   57664000ull          // 65536*4    =    262,144
#define HIST2_OFF   57926144ull          // 65536*4    =    262,144
#define SCAL_OFF    58188288ull          // 64*4
#define SEL_OFF     58188544ull          // 8192*8     =     65,536
#define TOPIDX_OFF  58254080ull          // 6000*4
#define BOXES_OFF   58278080ull          // 6000*4*4
#define VALID_OFF   58374080ull          // 6000*4
#define MASK_OFF    58398080ull          // 6000*94*8  =  4,512,000
#define W1R_OFF     62910080ull          // [32][256][9][8]*4 = 2,359,296
#define WCR_OFF     65269376ull          // 9*256*4

__device__ __forceinline__ unsigned fkey(float fv) {
    unsigned u = __float_as_uint(fv);
    return (u & 0x80000000u) ? ~u : (u | 0x80000000u);  // monotone: bigger float -> bigger key
}

// ---- clear histograms + repack weights, one launch ----
// w1r layout: [wg=oc>>3][ic][k][oc&7] -> per-wave (ic) weights are 72 contiguous
// floats, wave-uniform address -> s_load into SGPRs.
__global__ __launch_bounds__(256) void k_init(const float* __restrict__ w1,
                                              const float* __restrict__ wcls,
                                              unsigned* __restrict__ hist1,
                                              float* __restrict__ w1r,
                                              float* __restrict__ wcr) {
    int e = blockIdx.x * 256 + threadIdx.x;
    if (e < 131136) hist1[e] = 0u;
    int e1 = e - 131136;
    if (e1 >= 0 && e1 < 589824) {
        int oc = e1 / 2304; int rem = e1 % 2304; int ic = rem / 9; int k = rem % 9;
        int wg = oc >> 3, o = oc & 7;
        w1r[(((size_t)wg * 256 + ic) * 9 + k) * 8 + o] = w1[e1];
    } else if (e1 >= 589824 && e1 < 589824 + 2304) {
        int e2 = e1 - 589824; int a = e2 / 256; int c = e2 % 256;
        wcr[c * 9 + a] = wcls[e2];
    }
}

// ---- 3x3 conv + bias + relu. SGPR-weight conv with register-prefetch pipeline. ----
// Block: 32x * 8y spatial, 4 waves x 8oc. Thread: 4x * 8oc (32 acc VGPRs).
// Weights: wave-uniform s_load -> v_fma_f32 SGPR operand (no LDS/VGPR weight cost).
// Input: stride-36 LDS rows, 16B-aligned b128+b64 reads, bank-uniform.
// Next chunk's halo prefetched into registers BEFORE compute -> HBM latency
// overlaps FMA work instead of draining at the barrier.
// FMA order per accumulator: ic -> ci -> ky -> kx (bitwise-stable vs prior rounds).
__global__ __launch_bounds__(256, 4) void k_conv1(const float* __restrict__ f,
                                                  const float* __restrict__ w1r,
                                                  const float* __restrict__ b1,
                                                  float* __restrict__ xo) {
    __shared__ __align__(16) float sI[8 * 10 * 36];   // 11,520 B
    int tid = threadIdx.x;
    int lane = tid & 63;
    int wgl = __builtin_amdgcn_readfirstlane(tid >> 6);  // wave id 0..3 (uniform)
    int xg = lane & 7;            // 8 x-subtiles of 4
    int yg = lane >> 3;           // 8 rows
    int X0 = blockIdx.x * 32;
    int Y0 = blockIdx.y * 8;
    int wg = blockIdx.z * 4 + wgl;   // oc-group of 8 (0..31), wave-uniform
    int y = Y0 + yg;                 // 200 % 8 == 0 -> always valid
    int xbase = X0 + xg * 4;

    // staging slot precompute (loop-invariant across chunks)
    int off[11]; int lds[11]; bool ok[11];
#pragma unroll
    for (int it = 0; it < 11; it++) {
        int l = tid + it * 256;
        int ci = l / 340; int r = l - ci * 340; int ry = r / 34; int rx = r - ry * 34;
        int gx = X0 - 1 + rx, gy = Y0 - 1 + ry;
        ok[it] = (l < CHUNK_W) && gx >= 0 && gx < W_ && gy >= 0 && gy < H_;
        off[it] = ci * HW + gy * W_ + gx;
        lds[it] = (ci * 10 + ry) * 36 + rx;
    }
    float rbuf[11];
#pragma unroll
    for (int it = 0; it < 11; it++)
        rbuf[it] = ok[it] ? f[off[it]] : 0.f;       // prefetch chunk 0

    float acc[8][4];
#pragma unroll
    for (int o = 0; o < 8; o++)
#pragma unroll
        for (int i = 0; i < 4; i++) acc[o][i] = 0.f;

    const float* wbase = w1r + (size_t)wg * 256 * 72;

    for (int ic0 = 0; ic0 < 256; ic0 += 8) {
        __syncthreads();
#pragma unroll
        for (int it = 0; it < 11; it++)
            if (tid + it * 256 < CHUNK_W) sI[lds[it]] = rbuf[it];
        __syncthreads();
        if (ic0 < 248) {
            const float* fn = f + (size_t)(ic0 + 8) * HW;
#pragma unroll
            for (int it = 0; it < 11; it++)
                rbuf[it] = ok[it] ? fn[off[it]] : 0.f;   // prefetch next chunk
        }
        for (int ci = 0; ci < 8; ci++) {
            const float* wp = wbase + (size_t)(ic0 + ci) * 72;  // wave-uniform -> SGPR
#pragma unroll
            for (int ky = 0; ky < 3; ky++) {
                const float* irow = &sI[(ci * 10 + yg + ky) * 36 + xg * 4];
                float in[6];
#pragma unroll
                for (int j = 0; j < 6; j++) in[j] = irow[j];
                const float* wrow = wp + ky * 24;   // [kx][8]
#pragma unroll
                for (int kx = 0; kx < 3; kx++) {
#pragma unroll
                    for (int o = 0; o < 8; o++) {
                        float w = wrow[kx * 8 + o];   // SGPR operand
#pragma unroll
                        for (int i = 0; i < 4; i++)
                            acc[o][i] = fmaf(w, in[i + kx], acc[o][i]);
                    }
                }
            }
        }
    }
    // epilogue: bias + relu + store (x may exceed 271 on last x-tile)
#pragma unroll
    for (int o = 0; o < 8; o++) {
        int oc = wg * 8 + o;
        float bv = b1[oc];
        float* orow = xo + (size_t)oc * HW + y * W_ + xbase;
        float v0 = fmaxf(acc[o][0] + bv, 0.f), v1 = fmaxf(acc[o][1] + bv, 0.f);
        float v2 = fmaxf(acc[o][2] + bv, 0.f), v3 = fmaxf(acc[o][3] + bv, 0.f);
        if (xbase + 3 < W_) {
            *(float4*)orow = make_float4(v0, v1, v2, v3);
        } else {
            float vv[4] = {v0, v1, v2, v3};
            for (int i = 0; i < 4; i++)
                if (xbase + i < W_) orow[i] = vv[i];
        }
    }
}

// ---- 1x1 cls conv -> conf[p*9+a], fused radix histogram pass 1 ----
__global__ __launch_bounds__(256) void k_cls(const float* __restrict__ x,
                                             const float* __restrict__ wcr,
                                             const float* __restrict__ bc,
                                             float* __restrict__ conf,
                                             unsigned* __restrict__ hist) {
    int p = blockIdx.x * 256 + threadIdx.x;
    if (p >= HW) return;
    float acc[9];
#pragma unroll
    for (int a = 0; a < 9; a++) acc[a] = 0.f;
    for (int c = 0; c < 256; c++) {
        float xv = x[c * HW + p];
        const float* wp = wcr + c * 9;  // uniform -> s_load
#pragma unroll
        for (int a = 0; a < 9; a++) acc[a] = fmaf(wp[a], xv, acc[a]);
    }
#pragma unroll
    for (int a = 0; a < 9; a++) {
        float v = acc[a] + bc[a];
        conf[p * 9 + a] = v;
        atomicAdd(&hist[fkey(v) >> 16], 1u);
    }
}

__global__ __launch_bounds__(256) void k_hist2(const float* __restrict__ conf,
                                               const unsigned* __restrict__ scal, unsigned* hist) {
    int n = blockIdx.x * 256 + threadIdx.x;
    if (n >= NANCH) return;
    unsigned key = fkey(conf[n]);
    if ((key >> 16) == scal[0]) atomicAdd(&hist[key & 0xFFFFu], 1u);
}

// ---- descending scan of 65536-bin histogram, find bin of the target-th largest ----
__global__ __launch_bounds__(1024) void k_scan(const unsigned* __restrict__ hist,
                                               unsigned* scal, int mode) {
    __shared__ unsigned ssum[1024];
    int t = threadIdx.x;
    unsigned target = 6000u - (mode ? scal[1] : 0u);
    int base = 65535 - t * 64;
    unsigned s = 0;
    for (int k = 0; k < 64; k++) s += hist[base - k];
    ssum[t] = s;
    __syncthreads();
    for (int off = 1; off < 1024; off <<= 1) {
        unsigned v = (t >= off) ? ssum[t - off] : 0u;
        __syncthreads();
        ssum[t] += v;
        __syncthreads();
    }
    unsigned incl = ssum[t], excl = incl - s;
    if (excl < target && target <= incl) {
        unsigned run = excl;
        for (int k = 0; k < 64; k++) {
            unsigned c = hist[base - k];
            if (run + c >= target) { scal[2 * mode] = (unsigned)(base - k); scal[2 * mode + 1] = run; break; }
            run += c;
        }
    }
}

// ---- gather all keys >= threshold (ties after strict-greater block) ----
__global__ __launch_bounds__(256) void k_gather(const float* __restrict__ conf,
                                                unsigned* scal, unsigned long long* sel) {
    int n = blockIdx.x * 256 + threadIdx.x;
    if (n >= NANCH) return;
    unsigned B1 = scal[0], cnt1 = scal[1], B2 = scal[2], cnt2 = scal[3];
    unsigned T = (B1 << 16) | B2;
    unsigned key = fkey(conf[n]);
    if (key < T) return;
    unsigned long long kk = ((unsigned long long)(~key) << 32) | (unsigned)n;  // asc sort => score desc, idx asc
    if (key > T) {
        unsigned pos = atomicAdd(&scal[4], 1u);
        if (pos < 8192u) sel[pos] = kk;
    } else {
        unsigned pos = cnt1 + cnt2 + atomicAdd(&scal[5], 1u);
        if (pos < 8192u) sel[pos] = kk;
    }
}

// ---- one-block bitonic sort of 8192 keys, emit top-6000 indices ----
__global__ __launch_bounds__(1024) void k_sort(const unsigned* __restrict__ scal,
                                               const unsigned long long* __restrict__ sel,
                                               unsigned* __restrict__ topidx) {
    __shared__ unsigned long long sk[8192];
    unsigned G = scal[1] + scal[3];
    unsigned filled = G + scal[5];
    if (filled > 8192u) filled = 8192u;
    for (int i = threadIdx.x; i < 8192; i += 1024)
        sk[i] = (i < (int)filled) ? sel[i] : 0xFFFFFFFFFFFFFFFFull;
    __syncthreads();
    for (int k = 2; k <= 8192; k <<= 1) {
        for (int j = k >> 1; j > 0; j >>= 1) {
            for (int i = threadIdx.x; i < 8192; i += 1024) {
                int l = i ^ j;
                if (l > i) {
                    unsigned long long a = sk[i], b = sk[l];
                    bool up = ((i & k) == 0);
                    if ((a > b) == up) { sk[i] = b; sk[l] = a; }
                }
            }
            __syncthreads();
        }
    }
    for (int r = threadIdx.x; r < PRE_N; r += 1024)
        topidx[r] = (unsigned)(sk[r] & 0xFFFFFFFFull);
}

// ---- per-proposal: reg conv (4 channels), anchor, decode, clip, valid ----
__global__ __launch_bounds__(64) void k_prop(const float* __restrict__ x,
                                             const float* __restrict__ wreg,
                                             const float* __restrict__ breg,
                                             const unsigned* __restrict__ topidx,
                                             const int* __restrict__ imh, const int* __restrict__ imw,
                                             float* __restrict__ boxes, int* __restrict__ valid) {
    int r = blockIdx.x;
    int lane = threadIdx.x;
    unsigned n = topidx[r];
    int a = (int)(n % 9u); int p = (int)(n / 9u);
    const float* wr = wreg + (4 * a) * 256;
    float s0 = 0, s1 = 0, s2 = 0, s3 = 0;
    for (int c = lane; c < 256; c += 64) {
        float xv = x[c * HW + p];
        s0 = fmaf(wr[c], xv, s0);
        s1 = fmaf(wr[256 + c], xv, s1);
        s2 = fmaf(wr[512 + c], xv, s2);
        s3 = fmaf(wr[768 + c], xv, s3);
    }
#pragma unroll
    for (int off = 32; off >= 1; off >>= 1) {
        s0 += __shfl_down(s0, off);
        s1 += __shfl_down(s1, off);
        s2 += __shfl_down(s2, off);
        s3 += __shfl_down(s3, off);
    }
    if (lane == 0) {
        float dx = s0 + breg[4 * a], dy = s1 + breg[4 * a + 1];
        float dw = s2 + breg[4 * a + 2], dh = s3 + breg[4 * a + 3];
        int wi = p % W_, hi = p / W_;
        const double SC[3] = {32.0, 64.0, 128.0};
        const double RT[3] = {0.5, 1.0, 2.0};
        double sd = SC[a / 3], rd = RT[a % 3];
        double wb = sd * sqrt(1.0 / rd), hb = sd * sqrt(rd);
        float bx1 = (float)(-wb * 0.5), by1 = (float)(-hb * 0.5);
        float bx2 = (float)(wb * 0.5),  by2 = (float)(hb * 0.5);
        float cxs = ((float)wi + 0.5f) * 4.0f, cys = ((float)hi + 0.5f) * 4.0f;
        float x1a = cxs + bx1, y1a = cys + by1, x2a = cxs + bx2, y2a = cys + by2;
        float wa = x2a - x1a, ha = y2a - y1a;
        float cxa = x1a + 0.5f * wa, cya = y1a + 0.5f * ha;
        float cx = dx * wa + cxa, cy = dy * ha + cya;
        float ww = expf(dw) * wa, hh = expf(dh) * ha;
        float X1 = cx - 0.5f * ww, Y1 = cy - 0.5f * hh;
        float X2 = cx + 0.5f * ww, Y2 = cy + 0.5f * hh;
        float Wf = (float)(*imw), Hf = (float)(*imh);
        X1 = fminf(fmaxf(X1, 0.f), Wf); Y1 = fminf(fmaxf(Y1, 0.f), Hf);
        X2 = fminf(fmaxf(X2, 0.f), Wf); Y2 = fminf(fmaxf(Y2, 0.f), Hf);
        boxes[4 * r] = X1; boxes[4 * r + 1] = Y1; boxes[4 * r + 2] = X2; boxes[4 * r + 3] = Y2;
        valid[r] = ((X2 - X1) >= 1.0f && (Y2 - Y1) >= 1.0f) ? 1 : 0;
    }
}

// ---- NMS IoU bitmask: mask[i][jw] bit b = (j=jw*64+b > i) && iou>0.7 ----
__global__ __launch_bounds__(256) void k_mask(const float* __restrict__ boxes,
                                              unsigned long long* __restrict__ mask) {
    __shared__ float jb[256];
    int jw = blockIdx.x;
    int i = blockIdx.y * 256 + threadIdx.x;
    {
        int idx = jw * 256 + threadIdx.x;
        jb[threadIdx.x] = (idx < PRE_N * 4) ? boxes[idx] : 0.f;
    }
    __syncthreads();
    if (i >= PRE_N) return;
    float ax1 = boxes[4 * i], ay1 = boxes[4 * i + 1], ax2 = boxes[4 * i + 2], ay2 = boxes[4 * i + 3];
    float aarea = (ax2 - ax1) * (ay2 - ay1);
    unsigned long long m = 0;
    int jbase = jw * 64;
    for (int b = 0; b < 64; b++) {
        int j = jbase + b;
        if (j <= i || j >= PRE_N) continue;
        float bx1 = jb[4 * b], by1 = jb[4 * b + 1], bx2 = jb[4 * b + 2], by2 = jb[4 * b + 3];
        float barea = (bx2 - bx1) * (by2 - by1);
        float xx1 = fmaxf(ax1, bx1), yy1 = fmaxf(ay1, by1);
        float xx2 = fminf(ax2, bx2), yy2 = fminf(ay2, by2);
        float w = fmaxf(xx2 - xx1, 0.f), h = fmaxf(yy2 - yy1, 0.f);
        float inter = w * h;
        float iou = inter / (aarea + barea - inter + 1e-9f);
        if (iou > 0.7f) m |= (1ull << b);
    }
    mask[(size_t)i * NWORDS + jw] = m;
}

// ---- greedy scan: diagonal masks preloaded to LDS; serial part iterates kept bits ----
__global__ __launch_bounds__(128) void k_scan_nms(const unsigned long long* __restrict__ mask,
                                                  const int* __restrict__ valid,
                                                  const float* __restrict__ boxes,
                                                  float* __restrict__ out) {
    __shared__ unsigned long long diag[NWORDS][64];   // 48,128 B
    __shared__ unsigned long long removed[NWORDS];
    __shared__ unsigned long long validw[NWORDS];
    __shared__ int keepList[POST_N];
    __shared__ int cnt;
    __shared__ unsigned long long keptbits;
    int t = threadIdx.x;
    if (t < NWORDS) { removed[t] = 0ull; validw[t] = 0ull; }
    if (t == 0) cnt = 0;
    __syncthreads();
    for (int l = t; l < NWORDS * 64; l += 128) {
        int w = l >> 6, b = l & 63;
        int i = w * 64 + b;
        diag[w][b] = (i < PRE_N) ? mask[(size_t)i * NWORDS + w] : 0ull;
    }
    for (int i = t; i < PRE_N; i += 128)
        if (valid[i]) atomicOr(&validw[i >> 6], 1ull << (i & 63));
    __syncthreads();
    for (int w = 0; w < NWORDS; w++) {
        unsigned long long candw = validw[w] & ~removed[w];  // uniform (LDS, post-sync)
        if (!candw) continue;
        if (t == 0) {
            unsigned long long cand = candw;
            unsigned long long kb = 0ull;
            int c = cnt;
            while (cand && c < POST_N) {
                int b = __ffsll((unsigned long long)cand) - 1;
                keepList[c++] = w * 64 + b;
                kb |= 1ull << b;
                cand &= ~(1ull << b);
                cand &= ~diag[w][b];
            }
            cnt = c; keptbits = kb;
        }
        __syncthreads();
        if (cnt >= POST_N) break;
        unsigned long long kb = keptbits;
        if (kb) {
            for (int w2 = w + 1 + t; w2 < NWORDS; w2 += 128) {
                unsigned long long acc2 = removed[w2];
                unsigned long long tt = kb;
                while (tt) {
                    int b = __ffsll((unsigned long long)tt) - 1;
                    tt &= tt - 1;
                    acc2 |= mask[(size_t)(w * 64 + b) * NWORDS + w2];
                }
                removed[w2] = acc2;
            }
        }
        __syncthreads();
    }
    __syncthreads();
    int c = cnt;
    for (int e = t; e < POST_N * 4; e += 128) {
        int r = e >> 2;
        out[e] = (r < c) ? boxes[4 * keepList[r] + (e & 3)] : 0.f;
    }
}

extern "C" void kernel_launch(void* const* d_in, const int* in_sizes, int n_in,
                              void* d_out, int out_size, void* d_ws, size_t ws_size,
                              hipStream_t stream) {
    const float* feature = (const float*)d_in[0];
    const float* w1   = (const float*)d_in[1];
    const float* b1   = (const float*)d_in[2];
    const float* wcls = (const float*)d_in[3];
    const float* bcls = (const float*)d_in[4];
    const float* wreg = (const float*)d_in[5];
    const float* breg = (const float*)d_in[6];
    const int* imh = (const int*)d_in[7];
    const int* imw = (const int*)d_in[8];

    char* ws = (char*)d_ws;
    float* xbuf  = (float*)(ws + X_OFF);
    float* conf  = (float*)(ws + CONF_OFF);
    unsigned* hist1 = (unsigned*)(ws + HIST1_OFF);
    unsigned* hist2 = (unsigned*)(ws + HIST2_OFF);
    unsigned* scal  = (unsigned*)(ws + SCAL_OFF);
    unsigned long long* sel = (unsigned long long*)(ws + SEL_OFF);
    unsigned* topidx = (unsigned*)(ws + TOPIDX_OFF);
    float* boxes = (float*)(ws + BOXES_OFF);
    int* valid   = (int*)(ws + VALID_OFF);
    unsigned long long* mask = (unsigned long long*)(ws + MASK_OFF);
    float* w1r = (float*)(ws + W1R_OFF);
    float* wcr = (float*)(ws + WCR_OFF);
    float* outF = (float*)d_out;

    hipLaunchKernelGGL(k_init,   dim3(2826), dim3(256), 0, stream, w1, wcls, hist1, w1r, wcr);
    hipLaunchKernelGGL(k_conv1,  dim3(9, 25, 8), dim3(256), 0, stream, feature, w1r, b1, xbuf);
    hipLaunchKernelGGL(k_cls,    dim3(213),  dim3(256), 0, stream, xbuf, wcr, bcls, conf, hist1);
    hipLaunchKernelGGL(k_scan,   dim3(1),    dim3(1024), 0, stream, hist1, scal, 0);
    hipLaunchKernelGGL(k_hist2,  dim3(1913), dim3(256), 0, stream, conf, scal, hist2);
    hipLaunchKernelGGL(k_scan,   dim3(1),    dim3(1024), 0, stream, hist2, scal, 1);
    hipLaunchKernelGGL(k_gather, dim3(1913), dim3(256), 0, stream, conf, scal, sel);
    hipLaunchKernelGGL(k_sort,   dim3(1),    dim3(1024), 0, stream, scal, sel, topidx);
    hipLaunchKernelGGL(k_prop,   dim3(PRE_N), dim3(64), 0, stream, xbuf, wreg, breg, topidx, imh, imw, boxes, valid);
    hipLaunchKernelGGL(k_mask,   dim3(NWORDS, 24), dim3(256), 0, stream, boxes, mask);
    hipLaunchKernelGGL(k_scan_nms, dim3(1), dim3(128), 0, stream, mask, valid, boxes, outF);
}

// Round 6
// 1593.683 us; speedup vs baseline: 1.2790x; 1.1251x over previous
//
#include <hip/hip_runtime.h>
#include <hip/hip_bf16.h>
#include <math.h>

#define H_ 200
#define W_ 272
#define C_ 256
#define HW 54400
#define NANCH 489600
#define PRE_N 6000
#define POST_N 1000
#define NWORDS 94   // ceil(6000/64)
#define CHUNK_W 2720  // 8 ic * 10 rows * 34 cols halo

// ---- workspace layout (bytes) ----
#define X_OFF       0ull                 // 256*54400*4 = 55,705,600
#define CONF_OFF    55705600ull          // 489600*4   =  1,958,400
#define HIST1_OFF   57664000ull          // 65536*4    =    262,144
#define HIST2_OFF   57926144ull          // 65536*4    =    262,144
#define SCAL_OFF    58188288ull          // 64*4
#define SEL_OFF     58188544ull          // 8192*8     =     65,536
#define TOPIDX_OFF  58254080ull          // 6000*4
#define BOXES_OFF   58278080ull          // 6000*4*4
#define VALID_OFF   58374080ull          // 6000*4
#define MASK_OFF    58398080ull          // 6000*94*8  =  4,512,000
#define W1R_OFF     62910080ull          // [32][256][9][8]*4 = 2,359,296
#define WCR_OFF     65269376ull          // 9*256*4

__device__ __forceinline__ unsigned fkey(float fv) {
    unsigned u = __float_as_uint(fv);
    return (u & 0x80000000u) ? ~u : (u | 0x80000000u);  // monotone: bigger float -> bigger key
}

// ---- clear histograms + repack weights, one launch ----
// w1r layout: [wg=oc>>3][ic][k][oc&7] -> per-wave (ic) weights are 72 contiguous
// floats, wave-uniform address -> s_load into SGPRs.
__global__ __launch_bounds__(256) void k_init(const float* __restrict__ w1,
                                              const float* __restrict__ wcls,
                                              unsigned* __restrict__ hist1,
                                              float* __restrict__ w1r,
                                              float* __restrict__ wcr) {
    int e = blockIdx.x * 256 + threadIdx.x;
    if (e < 131136) hist1[e] = 0u;
    int e1 = e - 131136;
    if (e1 >= 0 && e1 < 589824) {
        int oc = e1 / 2304; int rem = e1 % 2304; int ic = rem / 9; int k = rem % 9;
        int wg = oc >> 3, o = oc & 7;
        w1r[(((size_t)wg * 256 + ic) * 9 + k) * 8 + o] = w1[e1];
    } else if (e1 >= 589824 && e1 < 589824 + 2304) {
        int e2 = e1 - 589824; int a = e2 / 256; int c = e2 % 256;
        wcr[c * 9 + a] = wcls[e2];
    }
}

// ---- 3x3 conv + bias + relu. SGPR-weight conv, double-buffered LDS. ----
// Block: 32x * 8y spatial, 4 waves x 8oc. Thread: 4x * 8oc (32 acc VGPRs).
// Weights: wave-uniform s_load -> v_fma_f32 SGPR operand.
// Input: stride-36 LDS rows, EXPLICIT float4+float2 reads (b128/b64,
// bank-quad = (row+xg) mod 8, distinct per 8-lane group -> conflict-free).
// Double buffer: prefetch chunk k+1 (global->reg) issued BEFORE compute of
// chunk k, LDS-written to the other buffer AFTER compute; ONE barrier/chunk.
// FMA order per accumulator: ic -> ci -> ky -> kx (bitwise-stable vs R1-R5).
__global__ __launch_bounds__(256) void k_conv1(const float* __restrict__ f,
                                               const float* __restrict__ w1r,
                                               const float* __restrict__ b1,
                                               float* __restrict__ xo) {
    __shared__ __align__(16) float sI[2][2880];   // 2 x 11,520 B
    int tid = threadIdx.x;
    int lane = tid & 63;
    int wgl = __builtin_amdgcn_readfirstlane(tid >> 6);  // wave id 0..3 (uniform)
    int xg = lane & 7;            // 8 x-subtiles of 4
    int yg = lane >> 3;           // 8 rows
    int X0 = blockIdx.x * 32;
    int Y0 = blockIdx.y * 8;
    int wg = blockIdx.z * 4 + wgl;   // oc-group of 8 (0..31), wave-uniform
    int y = Y0 + yg;                 // 200 % 8 == 0 -> always valid
    int xbase = X0 + xg * 4;

    // staging slot precompute (loop-invariant across chunks)
    int off[11]; int lds[11]; bool ok[11];
#pragma unroll
    for (int it = 0; it < 11; it++) {
        int l = tid + it * 256;
        int ci = l / 340; int r = l - ci * 340; int ry = r / 34; int rx = r - ry * 34;
        int gx = X0 - 1 + rx, gy = Y0 - 1 + ry;
        ok[it] = (l < CHUNK_W) && gx >= 0 && gx < W_ && gy >= 0 && gy < H_;
        off[it] = ci * HW + gy * W_ + gx;
        lds[it] = (ci * 10 + ry) * 36 + rx;
    }
    float rbuf[11];
#pragma unroll
    for (int it = 0; it < 11; it++)
        rbuf[it] = ok[it] ? f[off[it]] : 0.f;       // prefetch chunk 0
#pragma unroll
    for (int it = 0; it < 11; it++)
        if (tid + it * 256 < CHUNK_W) sI[0][lds[it]] = rbuf[it];
    __syncthreads();

    float acc[8][4];
#pragma unroll
    for (int o = 0; o < 8; o++)
#pragma unroll
        for (int i = 0; i < 4; i++) acc[o][i] = 0.f;

    const float* wbase = w1r + (size_t)wg * 256 * 72;

    int cur = 0;
    for (int ic0 = 0; ic0 < 256; ic0 += 8) {
        // issue next chunk's global loads before compute (latency overlaps FMAs)
        if (ic0 < 248) {
            const float* fn = f + (size_t)(ic0 + 8) * HW;
#pragma unroll
            for (int it = 0; it < 11; it++)
                rbuf[it] = ok[it] ? fn[off[it]] : 0.f;
        }
        const float* sbuf = sI[cur];
        for (int ci = 0; ci < 8; ci++) {
            const float* wp = wbase + (size_t)(ic0 + ci) * 72;  // wave-uniform -> SGPR
#pragma unroll
            for (int ky = 0; ky < 3; ky++) {
                const float* irow = &sbuf[(ci * 10 + yg + ky) * 36 + xg * 4];
                float4 va = *(const float4*)irow;          // ds_read_b128
                float2 vb = *(const float2*)(irow + 4);    // ds_read_b64
                float in[6] = {va.x, va.y, va.z, va.w, vb.x, vb.y};
                const float* wrow = wp + ky * 24;   // [kx][8]
#pragma unroll
                for (int kx = 0; kx < 3; kx++) {
#pragma unroll
                    for (int o = 0; o < 8; o++) {
                        float w = wrow[kx * 8 + o];   // SGPR operand
#pragma unroll
                        for (int i = 0; i < 4; i++)
                            acc[o][i] = fmaf(w, in[i + kx], acc[o][i]);
                    }
                }
            }
        }
        // stage next chunk into the other buffer, single barrier per chunk
        if (ic0 < 248) {
#pragma unroll
            for (int it = 0; it < 11; it++)
                if (tid + it * 256 < CHUNK_W) sI[cur ^ 1][lds[it]] = rbuf[it];
        }
        __syncthreads();
        cur ^= 1;
    }
    // epilogue: bias + relu + store (x may exceed 271 on last x-tile)
#pragma unroll
    for (int o = 0; o < 8; o++) {
        int oc = wg * 8 + o;
        float bv = b1[oc];
        float* orow = xo + (size_t)oc * HW + y * W_ + xbase;
        float v0 = fmaxf(acc[o][0] + bv, 0.f), v1 = fmaxf(acc[o][1] + bv, 0.f);
        float v2 = fmaxf(acc[o][2] + bv, 0.f), v3 = fmaxf(acc[o][3] + bv, 0.f);
        if (xbase + 3 < W_) {
            *(float4*)orow = make_float4(v0, v1, v2, v3);
        } else {
            float vv[4] = {v0, v1, v2, v3};
            for (int i = 0; i < 4; i++)
                if (xbase + i < W_) orow[i] = vv[i];
        }
    }
}

// ---- 1x1 cls conv -> conf[p*9+a], fused radix histogram pass 1 ----
__global__ __launch_bounds__(256) void k_cls(const float* __restrict__ x,
                                             const float* __restrict__ wcr,
                                             const float* __restrict__ bc,
                                             float* __restrict__ conf,
                                             unsigned* __restrict__ hist) {
    int p = blockIdx.x * 256 + threadIdx.x;
    if (p >= HW) return;
    float acc[9];
#pragma unroll
    for (int a = 0; a < 9; a++) acc[a] = 0.f;
    for (int c = 0; c < 256; c++) {
        float xv = x[c * HW + p];
        const float* wp = wcr + c * 9;  // uniform -> s_load
#pragma unroll
        for (int a = 0; a < 9; a++) acc[a] = fmaf(wp[a], xv, acc[a]);
    }
#pragma unroll
    for (int a = 0; a < 9; a++) {
        float v = acc[a] + bc[a];
        conf[p * 9 + a] = v;
        atomicAdd(&hist[fkey(v) >> 16], 1u);
    }
}

__global__ __launch_bounds__(256) void k_hist2(const float* __restrict__ conf,
                                               const unsigned* __restrict__ scal, unsigned* hist) {
    int n = blockIdx.x * 256 + threadIdx.x;
    if (n >= NANCH) return;
    unsigned key = fkey(conf[n]);
    if ((key >> 16) == scal[0]) atomicAdd(&hist[key & 0xFFFFu], 1u);
}

// ---- descending scan of 65536-bin histogram, find bin of the target-th largest ----
__global__ __launch_bounds__(1024) void k_scan(const unsigned* __restrict__ hist,
                                               unsigned* scal, int mode) {
    __shared__ unsigned ssum[1024];
    int t = threadIdx.x;
    unsigned target = 6000u - (mode ? scal[1] : 0u);
    int base = 65535 - t * 64;
    unsigned s = 0;
    for (int k = 0; k < 64; k++) s += hist[base - k];
    ssum[t] = s;
    __syncthreads();
    for (int off = 1; off < 1024; off <<= 1) {
        unsigned v = (t >= off) ? ssum[t - off] : 0u;
        __syncthreads();
        ssum[t] += v;
        __syncthreads();
    }
    unsigned incl = ssum[t], excl = incl - s;
    if (excl < target && target <= incl) {
        unsigned run = excl;
        for (int k = 0; k < 64; k++) {
            unsigned c = hist[base - k];
            if (run + c >= target) { scal[2 * mode] = (unsigned)(base - k); scal[2 * mode + 1] = run; break; }
            run += c;
        }
    }
}

// ---- gather all keys >= threshold (ties after strict-greater block) ----
__global__ __launch_bounds__(256) void k_gather(const float* __restrict__ conf,
                                                unsigned* scal, unsigned long long* sel) {
    int n = blockIdx.x * 256 + threadIdx.x;
    if (n >= NANCH) return;
    unsigned B1 = scal[0], cnt1 = scal[1], B2 = scal[2], cnt2 = scal[3];
    unsigned T = (B1 << 16) | B2;
    unsigned key = fkey(conf[n]);
    if (key < T) return;
    unsigned long long kk = ((unsigned long long)(~key) << 32) | (unsigned)n;  // smaller = better rank
    if (key > T) {
        unsigned pos = atomicAdd(&scal[4], 1u);
        if (pos < 8192u) sel[pos] = kk;
    } else {
        unsigned pos = cnt1 + cnt2 + atomicAdd(&scal[5], 1u);
        if (pos < 8192u) sel[pos] = kk;
    }
}

// ---- exact rank by pairwise comparison (replaces bitonic sort) ----
// All keys distinct (index embedded). rank = #{j : sel[j] < sel[i]}.
// Scatter topidx[rank] = idx for rank < 6000. 32 blocks x 256 threads.
__global__ __launch_bounds__(256) void k_rank(const unsigned* __restrict__ scal,
                                              const unsigned long long* __restrict__ sel,
                                              unsigned* __restrict__ topidx) {
    __shared__ unsigned long long tile[2048];
    unsigned G = scal[1] + scal[3];
    unsigned filled = G + scal[5];
    if (filled > 8192u) filled = 8192u;
    int i = blockIdx.x * 256 + threadIdx.x;
    unsigned long long mykey = (i < (int)filled) ? sel[i] : 0xFFFFFFFFFFFFFFFFull;
    int rank = 0;
    for (int t0 = 0; t0 < 8192; t0 += 2048) {
        __syncthreads();
        for (int l = threadIdx.x; l < 2048; l += 256) {
            int j = t0 + l;
            tile[l] = (j < (int)filled) ? sel[j] : 0xFFFFFFFFFFFFFFFFull;
        }
        __syncthreads();
        for (int l = 0; l < 2048; l += 4) {   // broadcast LDS reads, 4-wide
            ulonglong2 p = *(const ulonglong2*)&tile[l];
            ulonglong2 q = *(const ulonglong2*)&tile[l + 2];
            rank += (p.x < mykey) + (p.y < mykey) + (q.x < mykey) + (q.y < mykey);
        }
    }
    if (i < (int)filled && rank < PRE_N)
        topidx[rank] = (unsigned)(mykey & 0xFFFFFFFFull);
}

// ---- per-proposal: reg conv (4 channels), anchor, decode, clip, valid ----
__global__ __launch_bounds__(64) void k_prop(const float* __restrict__ x,
                                             const float* __restrict__ wreg,
                                             const float* __restrict__ breg,
                                             const unsigned* __restrict__ topidx,
                                             const int* __restrict__ imh, const int* __restrict__ imw,
                                             float* __restrict__ boxes, int* __restrict__ valid) {
    int r = blockIdx.x;
    int lane = threadIdx.x;
    unsigned n = topidx[r];
    int a = (int)(n % 9u); int p = (int)(n / 9u);
    const float* wr = wreg + (4 * a) * 256;
    float s0 = 0, s1 = 0, s2 = 0, s3 = 0;
    for (int c = lane; c < 256; c += 64) {
        float xv = x[c * HW + p];
        s0 = fmaf(wr[c], xv, s0);
        s1 = fmaf(wr[256 + c], xv, s1);
        s2 = fmaf(wr[512 + c], xv, s2);
        s3 = fmaf(wr[768 + c], xv, s3);
    }
#pragma unroll
    for (int off = 32; off >= 1; off >>= 1) {
        s0 += __shfl_down(s0, off);
        s1 += __shfl_down(s1, off);
        s2 += __shfl_down(s2, off);
        s3 += __shfl_down(s3, off);
    }
    if (lane == 0) {
        float dx = s0 + breg[4 * a], dy = s1 + breg[4 * a + 1];
        float dw = s2 + breg[4 * a + 2], dh = s3 + breg[4 * a + 3];
        int wi = p % W_, hi = p / W_;
        const double SC[3] = {32.0, 64.0, 128.0};
        const double RT[3] = {0.5, 1.0, 2.0};
        double sd = SC[a / 3], rd = RT[a % 3];
        double wb = sd * sqrt(1.0 / rd), hb = sd * sqrt(rd);
        float bx1 = (float)(-wb * 0.5), by1 = (float)(-hb * 0.5);
        float bx2 = (float)(wb * 0.5),  by2 = (float)(hb * 0.5);
        float cxs = ((float)wi + 0.5f) * 4.0f, cys = ((float)hi + 0.5f) * 4.0f;
        float x1a = cxs + bx1, y1a = cys + by1, x2a = cxs + bx2, y2a = cys + by2;
        float wa = x2a - x1a, ha = y2a - y1a;
        float cxa = x1a + 0.5f * wa, cya = y1a + 0.5f * ha;
        float cx = dx * wa + cxa, cy = dy * ha + cya;
        float ww = expf(dw) * wa, hh = expf(dh) * ha;
        float X1 = cx - 0.5f * ww, Y1 = cy - 0.5f * hh;
        float X2 = cx + 0.5f * ww, Y2 = cy + 0.5f * hh;
        float Wf = (float)(*imw), Hf = (float)(*imh);
        X1 = fminf(fmaxf(X1, 0.f), Wf); Y1 = fminf(fmaxf(Y1, 0.f), Hf);
        X2 = fminf(fmaxf(X2, 0.f), Wf); Y2 = fminf(fmaxf(Y2, 0.f), Hf);
        boxes[4 * r] = X1; boxes[4 * r + 1] = Y1; boxes[4 * r + 2] = X2; boxes[4 * r + 3] = Y2;
        valid[r] = ((X2 - X1) >= 1.0f && (Y2 - Y1) >= 1.0f) ? 1 : 0;
    }
}

// ---- NMS IoU bitmask: mask[i][jw] bit b = (j=jw*64+b > i) && iou>0.7 ----
__global__ __launch_bounds__(256) void k_mask(const float* __restrict__ boxes,
                                              unsigned long long* __restrict__ mask) {
    __shared__ float jb[256];
    int jw = blockIdx.x;
    int i = blockIdx.y * 256 + threadIdx.x;
    {
        int idx = jw * 256 + threadIdx.x;
        jb[threadIdx.x] = (idx < PRE_N * 4) ? boxes[idx] : 0.f;
    }
    __syncthreads();
    if (i >= PRE_N) return;
    float ax1 = boxes[4 * i], ay1 = boxes[4 * i + 1], ax2 = boxes[4 * i + 2], ay2 = boxes[4 * i + 3];
    float aarea = (ax2 - ax1) * (ay2 - ay1);
    unsigned long long m = 0;
    int jbase = jw * 64;
    for (int b = 0; b < 64; b++) {
        int j = jbase + b;
        if (j <= i || j >= PRE_N) continue;
        float bx1 = jb[4 * b], by1 = jb[4 * b + 1], bx2 = jb[4 * b + 2], by2 = jb[4 * b + 3];
        float barea = (bx2 - bx1) * (by2 - by1);
        float xx1 = fmaxf(ax1, bx1), yy1 = fmaxf(ay1, by1);
        float xx2 = fminf(ax2, bx2), yy2 = fminf(ay2, by2);
        float w = fmaxf(xx2 - xx1, 0.f), h = fmaxf(yy2 - yy1, 0.f);
        float inter = w * h;
        float iou = inter / (aarea + barea - inter + 1e-9f);
        if (iou > 0.7f) m |= (1ull << b);
    }
    mask[(size_t)i * NWORDS + jw] = m;
}

// ---- greedy scan: diagonal masks preloaded to LDS; serial part iterates kept bits ----
__global__ __launch_bounds__(128) void k_scan_nms(const unsigned long long* __restrict__ mask,
                                                  const int* __restrict__ valid,
                                                  const float* __restrict__ boxes,
                                                  float* __restrict__ out) {
    __shared__ unsigned long long diag[NWORDS][64];   // 48,128 B
    __shared__ unsigned long long removed[NWORDS];
    __shared__ unsigned long long validw[NWORDS];
    __shared__ int keepList[POST_N];
    __shared__ int cnt;
    __shared__ unsigned long long keptbits;
    int t = threadIdx.x;
    if (t < NWORDS) { removed[t] = 0ull; validw[t] = 0ull; }
    if (t == 0) cnt = 0;
    __syncthreads();
    for (int l = t; l < NWORDS * 64; l += 128) {
        int w = l >> 6, b = l & 63;
        int i = w * 64 + b;
        diag[w][b] = (i < PRE_N) ? mask[(size_t)i * NWORDS + w] : 0ull;
    }
    for (int i = t; i < PRE_N; i += 128)
        if (valid[i]) atomicOr(&validw[i >> 6], 1ull << (i & 63));
    __syncthreads();
    for (int w = 0; w < NWORDS; w++) {
        unsigned long long candw = validw[w] & ~removed[w];  // uniform (LDS, post-sync)
        if (!candw) continue;
        if (t == 0) {
            unsigned long long cand = candw;
            unsigned long long kb = 0ull;
            int c = cnt;
            while (cand && c < POST_N) {
                int b = __ffsll((unsigned long long)cand) - 1;
                keepList[c++] = w * 64 + b;
                kb |= 1ull << b;
                cand &= ~(1ull << b);
                cand &= ~diag[w][b];
            }
            cnt = c; keptbits = kb;
        }
        __syncthreads();
        if (cnt >= POST_N) break;
        unsigned long long kb = keptbits;
        if (kb) {
            for (int w2 = w + 1 + t; w2 < NWORDS; w2 += 128) {
                unsigned long long acc2 = removed[w2];
                unsigned long long tt = kb;
                while (tt) {
                    int b = __ffsll((unsigned long long)tt) - 1;
                    tt &= tt - 1;
                    acc2 |= mask[(size_t)(w * 64 + b) * NWORDS + w2];
                }
                removed[w2] = acc2;
            }
        }
        __syncthreads();
    }
    __syncthreads();
    int c = cnt;
    for (int e = t; e < POST_N * 4; e += 128) {
        int r = e >> 2;
        out[e] = (r < c) ? boxes[4 * keepList[r] + (e & 3)] : 0.f;
    }
}

extern "C" void kernel_launch(void* const* d_in, const int* in_sizes, int n_in,
                              void* d_out, int out_size, void* d_ws, size_t ws_size,
                              hipStream_t stream) {
    const float* feature = (const float*)d_in[0];
    const float* w1   = (const float*)d_in[1];
    const float* b1   = (const float*)d_in[2];
    const float* wcls = (const float*)d_in[3];
    const float* bcls = (const float*)d_in[4];
    const float* wreg = (const float*)d_in[5];
    const float* breg = (const float*)d_in[6];
    const int* imh = (const int*)d_in[7];
    const int* imw = (const int*)d_in[8];

    char* ws = (char*)d_ws;
    float* xbuf  = (float*)(ws + X_OFF);
    float* conf  = (float*)(ws + CONF_OFF);
    unsigned* hist1 = (unsigned*)(ws + HIST1_OFF);
    unsigned* hist2 = (unsigned*)(ws + HIST2_OFF);
    unsigned* scal  = (unsigned*)(ws + SCAL_OFF);
    unsigned long long* sel = (unsigned long long*)(ws + SEL_OFF);
    unsigned* topidx = (unsigned*)(ws + TOPIDX_OFF);
    float* boxes = (float*)(ws + BOXES_OFF);
    int* valid   = (int*)(ws + VALID_OFF);
    unsigned long long* mask = (unsigned long long*)(ws + MASK_OFF);
    float* w1r = (float*)(ws + W1R_OFF);
    float* wcr = (float*)(ws + WCR_OFF);
    float* outF = (float*)d_out;

    hipLaunchKernelGGL(k_init,   dim3(2826), dim3(256), 0, stream, w1, wcls, hist1, w1r, wcr);
    hipLaunchKernelGGL(k_conv1,  dim3(9, 25, 8), dim3(256), 0, stream, feature, w1r, b1, xbuf);
    hipLaunchKernelGGL(k_cls,    dim3(213),  dim3(256), 0, stream, xbuf, wcr, bcls, conf, hist1);
    hipLaunchKernelGGL(k_scan,   dim3(1),    dim3(1024), 0, stream, hist1, scal, 0);
    hipLaunchKernelGGL(k_hist2,  dim3(1913), dim3(256), 0, stream, conf, scal, hist2);
    hipLaunchKernelGGL(k_scan,   dim3(1),    dim3(1024), 0, stream, hist2, scal, 1);
    hipLaunchKernelGGL(k_gather, dim3(1913), dim3(256), 0, stream, conf, scal, sel);
    hipLaunchKernelGGL(k_rank,   dim3(32),   dim3(256), 0, stream, scal, sel, topidx);
    hipLaunchKernelGGL(k_prop,   dim3(PRE_N), dim3(64), 0, stream, xbuf, wreg, breg, topidx, imh, imw, boxes, valid);
    hipLaunchKernelGGL(k_mask,   dim3(NWORDS, 24), dim3(256), 0, stream, boxes, mask);
    hipLaunchKernelGGL(k_scan_nms, dim3(1), dim3(128), 0, stream, mask, valid, boxes, outF);
}